// Round 1
// baseline (701.966 us; speedup 1.0000x reference)
//
#include <hip/hip_runtime.h>
#include <math.h>

// Problem constants
#define KJ 24
#define NV 6890
#define PREG 200
#define M_TOT (NV*3)          // 20670
#define KDIM 391              // 23*17
#define KW_STRIDE 20672       // padded so rows are 64B aligned, pad cols zeroed
#define QMT_STRIDE 256        // qm^T [k][p], padded p to 256 (p>=200 zeroed)

// Workspace layout (float offsets). Total = 12,374,512 floats = 47.2 MB.
#define ACC_OFF 0                              // [0]=ED [1]=EWi [2]=EW [3]=EA [4..26]=SK[j]
#define G_OFF   64                             // G' : 200 x 24 x 12
#define QMT_OFF (G_OFF + PREG*288)             // 57,664 : qm^T 391 x 256
#define KW_OFF  (QMT_OFF + KDIM*QMT_STRIDE)    // 157,760 : KW 391 x 20672
#define TP_OFF  (KW_OFF + KDIM*KW_STRIDE)      // 8,240,512 : T_p 200 x 20670 (p-major)

__constant__ int c_PARENT[24] = {0,0,0,0,1,2,3,4,5,6,7,8,9,9,9,12,13,14,16,17,18,19,20,21};
__constant__ int c_LEN[24]    = {4,3,3,3,3,3,3,3,3,2,2,2,4,3,3,2,3,3,3,3,3,3,2,2};
__constant__ int c_NBR[24][4] = {
  {0,1,2,3},{0,1,4,0},{0,2,5,0},{0,3,6,0},{1,4,7,0},{2,5,8,0},{3,6,9,0},{4,7,10,0},
  {5,8,11,0},{6,9,0,0},{7,10,0,0},{8,11,0,0},{12,13,14,15},{12,13,16,0},{12,14,17,0},
  {12,15,0,0},{13,16,18,0},{14,17,19,0},{16,18,20,0},{17,19,21,0},{18,20,22,0},
  {19,21,23,0},{20,22,0,0},{21,23,0,0}};

__device__ __forceinline__ float waveReduce(float v) {
  #pragma unroll
  for (int off = 32; off > 0; off >>= 1) v += __shfl_down(v, off, 64);
  return v;
}

// ---- init: zero accumulators + qm^T (incl. p-pad lanes) ----
__global__ __launch_bounds__(256) void kInit(float* __restrict__ ws) {
  int i = blockIdx.x * 256 + threadIdx.x;          // grid 391*256 == 100,096 exactly
  ws[QMT_OFF + i] = 0.f;
  if (i < 32) ws[ACC_OFF + i] = 0.f;
}

// ---- kernel A: per-p pose math -> G' (3x4 per joint) and qm^T ----
__global__ __launch_bounds__(64) void kA(const float* __restrict__ J,
                                         const float* __restrict__ theta,
                                         const float* __restrict__ beta2,
                                         float* __restrict__ ws) {
  int p = blockIdx.x, t = threadIdx.x;
  __shared__ float Gl[24][12];
  __shared__ float Gg[24][12];
  __shared__ float q[24][4];
  if (t < 24) {
    float x = theta[p*72 + 3*t + 0];
    float y = theta[p*72 + 3*t + 1];
    float z = theta[p*72 + 3*t + 2];
    float n2 = x*x + y*y + z*z;
    float ang = fmaxf(sqrtf(n2), 1e-8f);
    float ia = 1.f/ang;
    float ax = x*ia, ay = y*ia, az = z*ia;
    float c = cosf(ang), s = sinf(ang), C = 1.f - c;
    float jx = J[p*72+3*t], jy = J[p*72+3*t+1], jz = J[p*72+3*t+2];
    float tx = jx, ty = jy, tz = jz;
    if (t > 0) {
      int par = c_PARENT[t];
      tx -= J[p*72+3*par]; ty -= J[p*72+3*par+1]; tz -= J[p*72+3*par+2];
    }
    Gl[t][0]=c+C*ax*ax;   Gl[t][1]=C*ax*ay-s*az; Gl[t][2]=C*ax*az+s*ay; Gl[t][3]=tx;
    Gl[t][4]=C*ax*ay+s*az;Gl[t][5]=c+C*ay*ay;    Gl[t][6]=C*ay*az-s*ax; Gl[t][7]=ty;
    Gl[t][8]=C*ax*az-s*ay;Gl[t][9]=C*ay*az+s*ax; Gl[t][10]=c+C*az*az;   Gl[t][11]=tz;
    // quaternion (axis2quat)
    float ang2 = sqrtf(fmaxf(n2, 1e-16f));
    float inv2 = 1.f/ang2;
    float s2 = sinf(0.5f*ang2);
    q[t][0] = x*inv2*s2; q[t][1] = y*inv2*s2; q[t][2] = z*inv2*s2;
    q[t][3] = cosf(0.5f*ang2) - 1.f;
  }
  __syncthreads();
  if (t == 0) {  // sequential kinematic chain (parent[i] < i)
    #pragma unroll
    for (int i2 = 0; i2 < 12; i2++) Gg[0][i2] = Gl[0][i2];
    for (int i = 1; i < 24; i++) {
      int par = c_PARENT[i];
      for (int r = 0; r < 3; r++) {
        for (int c2 = 0; c2 < 4; c2++) {
          float v = Gg[par][r*4+0]*Gl[i][0+c2] + Gg[par][r*4+1]*Gl[i][4+c2]
                  + Gg[par][r*4+2]*Gl[i][8+c2];
          if (c2 == 3) v += Gg[par][r*4+3];
          Gg[i][r*4+c2] = v;
        }
      }
    }
  }
  __syncthreads();
  if (t < 24) {
    float jx = J[p*72+3*t], jy = J[p*72+3*t+1], jz = J[p*72+3*t+2];
    float* gp = ws + G_OFF + p*288 + t*12;
    #pragma unroll
    for (int r = 0; r < 3; r++) {
      float off = Gg[t][r*4+0]*jx + Gg[t][r*4+1]*jy + Gg[t][r*4+2]*jz;
      Gg[t][r*4+3] -= off;
    }
    #pragma unroll
    for (int i2 = 0; i2 < 12; i2++) gp[i2] = Gg[t][i2];
  }
  __syncthreads();
  float b2 = beta2[0];
  for (int e = t; e < KDIM; e += 64) {
    int j = e / 17, l = e - 17*j;
    int k = j + 1;
    float val = 0.f;
    if (l < 4*c_LEN[j] + 1) {            // SLICE_MASK row j
      if (l < 16) {
        int sidx = l >> 2, cc = l & 3;
        if (sidx < c_LEN[k]) val = q[c_NBR[k][sidx]][cc];
      }
      if (l == 4*c_LEN[k]) val += b2;    // BETA_POS row k
    }
    ws[QMT_OFF + e*QMT_STRIDE + p] = val;
  }
}

// ---- kernel KW: KW[k][m] = K[k][m] * relu(A[j][m/3]); also E_K per-slice sums ----
__global__ __launch_bounds__(256) void kKW(const float* __restrict__ K,
                                           const float* __restrict__ A,
                                           float* __restrict__ ws) {
  int k = blockIdx.y;
  int j = k / 17;
  int m = (blockIdx.x * 256 + threadIdx.x) * 2;
  float sq = 0.f;
  if (m < M_TOT) {  // M_TOT even, so m+1 < M_TOT too
    float2 kv = *(const float2*)(K + (size_t)k*M_TOT + m);
    float a0 = fmaxf(A[j*NV + m/3], 0.f);
    float a1 = fmaxf(A[j*NV + (m+1)/3], 0.f);
    sq = kv.x*kv.x + kv.y*kv.y;
    float2 o; o.x = kv.x*a0; o.y = kv.y*a1;
    *(float2*)(ws + KW_OFF + (size_t)k*KW_STRIDE + m) = o;
  } else if (m < KW_STRIDE) {
    float2 z; z.x = 0.f; z.y = 0.f;
    *(float2*)(ws + KW_OFF + (size_t)k*KW_STRIDE + m) = z;
  }
  sq = waveReduce(sq);
  __shared__ float tmp[4];
  int lane = threadIdx.x & 63, w = threadIdx.x >> 6;
  if (lane == 0) tmp[w] = sq;
  __syncthreads();
  if (threadIdx.x == 0)
    atomicAdd(ws + ACC_OFF + 4 + j, tmp[0]+tmp[1]+tmp[2]+tmp[3]);
}

// ---- kernel B: T_p(200 x 20670) = qm(200x391) @ KW(391x20670); lanes = p,
//      KW via wave-uniform (scalar) loads, LDS transpose -> p-major store ----
__global__ __launch_bounds__(256) void kB(float* __restrict__ ws) {
  const float* __restrict__ qmT = ws + QMT_OFF;
  const float* __restrict__ KW  = ws + KW_OFF;
  float* __restrict__ TP = ws + TP_OFF;
  int tid = threadIdx.x;            // lane-p (p >= 200 lanes compute zeros)
  int m0 = blockIdx.x * 32;
  float acc[32];
  #pragma unroll
  for (int i = 0; i < 32; i++) acc[i] = 0.f;
  const float* qp = qmT + tid;
  const float* kp = KW + m0;        // uniform across the wave -> s_load
  for (int k = 0; k < KDIM; k++) {
    float qv = qp[(size_t)k * QMT_STRIDE];
    #pragma unroll
    for (int mm = 0; mm < 32; mm++)
      acc[mm] = fmaf(qv, kp[mm], acc[mm]);
    kp += KW_STRIDE;
  }
  __shared__ float lds[32*257];     // [mm][p], stride 257 kills bank conflicts
  #pragma unroll
  for (int mm = 0; mm < 32; mm++) lds[mm*257 + tid] = acc[mm];
  __syncthreads();
  // store p-major: thread t handles (p = i*8 + t/32, mm = t%32)
  int g = tid >> 5, mm = tid & 31;
  int m = m0 + mm;
  #pragma unroll
  for (int i = 0; i < 25; i++) {
    int p = i*8 + g;
    if (m < M_TOT) TP[(size_t)p*M_TOT + m] = lds[mm*257 + p];
  }
}

// ---- kernel C: skinning + verts + E_D ----
__global__ __launch_bounds__(256) void kC(const float* __restrict__ V,
                                          const float* __restrict__ T,
                                          const float* __restrict__ Wp,
                                          float* ws,
                                          float* __restrict__ out) {
  int p = blockIdx.y;
  int n = blockIdx.x * 256 + threadIdx.x;
  float ed = 0.f;
  if (n < NV) {
    float w[24];
    float sum = 0.f;
    const float4* wp4 = (const float4*)(Wp + n*24);
    #pragma unroll
    for (int i = 0; i < 6; i++) {
      float4 v4 = wp4[i];
      w[4*i+0] = fmaxf(v4.x, 0.f); w[4*i+1] = fmaxf(v4.y, 0.f);
      w[4*i+2] = fmaxf(v4.z, 0.f); w[4*i+3] = fmaxf(v4.w, 0.f);
      sum += w[4*i+0]+w[4*i+1]+w[4*i+2]+w[4*i+3];
    }
    float inv = 1.f/(sum + 1e-8f);
    float M[12];
    #pragma unroll
    for (int i = 0; i < 12; i++) M[i] = 0.f;
    const float* gp = ws + G_OFF + p*288;   // uniform -> s_load
    #pragma unroll
    for (int k = 0; k < 24; k++) {
      float wc = w[k]*inv;
      #pragma unroll
      for (int i = 0; i < 12; i++) M[i] = fmaf(wc, gp[k*12+i], M[i]);
    }
    size_t base = (size_t)p*M_TOT + 3*n;
    float t0 = ws[TP_OFF + base+0] + T[base+0];
    float t1 = ws[TP_OFF + base+1] + T[base+1];
    float t2 = ws[TP_OFF + base+2] + T[base+2];
    float v0 = M[0]*t0 + M[1]*t1 + M[2]*t2  + M[3];
    float v1 = M[4]*t0 + M[5]*t1 + M[6]*t2  + M[7];
    float v2 = M[8]*t0 + M[9]*t1 + M[10]*t2 + M[11];
    out[1+base+0] = v0; out[1+base+1] = v1; out[1+base+2] = v2;
    float d0 = V[base+0]-v0, d1 = V[base+1]-v1, d2 = V[base+2]-v2;
    ed = d0*d0 + d1*d1 + d2*d2;
  }
  ed = waveReduce(ed);
  if ((threadIdx.x & 63) == 0) atomicAdd(ws + ACC_OFF + 0, ed);
}

// ---- kernel D: E_Wi, E_W (per-vertex W rows) + E_A (grid-stride) ----
__global__ __launch_bounds__(256) void kD(const float* __restrict__ Wp,
                                          const float* __restrict__ Wi,
                                          const float* __restrict__ A,
                                          float* __restrict__ ws) {
  int n = blockIdx.x * 256 + threadIdx.x;
  float ewi = 0.f, ew = 0.f, ea = 0.f;
  if (n < NV) {
    float w[24]; float sum = 0.f;
    const float4* wp4 = (const float4*)(Wp + n*24);
    #pragma unroll
    for (int i = 0; i < 6; i++) {
      float4 v4 = wp4[i];
      w[4*i+0] = fmaxf(v4.x, 0.f); w[4*i+1] = fmaxf(v4.y, 0.f);
      w[4*i+2] = fmaxf(v4.z, 0.f); w[4*i+3] = fmaxf(v4.w, 0.f);
      sum += w[4*i+0]+w[4*i+1]+w[4*i+2]+w[4*i+3];
    }
    float inv = 1.f/(sum + 1e-8f);
    #pragma unroll
    for (int k = 0; k < 24; k++) {
      float wc = w[k]*inv;
      ew += fabsf(wc);
      float d = wc - Wi[n*24+k];
      ewi += d*d;
    }
  }
  int tot = 23*NV;
  int stride = gridDim.x * 256;
  for (int i = blockIdx.x*256 + threadIdx.x; i < tot; i += stride)
    ea += fabsf(A[i]);
  ewi = waveReduce(ewi); ew = waveReduce(ew); ea = waveReduce(ea);
  if ((threadIdx.x & 63) == 0) {
    atomicAdd(ws + ACC_OFF + 1, ewi);
    atomicAdd(ws + ACC_OFF + 2, ew);
    atomicAdd(ws + ACC_OFF + 3, ea);
  }
}

// ---- kernel F: final energy combine ----
__global__ void kF(const int* __restrict__ epoch, const float* __restrict__ ws,
                   float* __restrict__ out) {
  if (threadIdx.x == 0 && blockIdx.x == 0) {
    float e    = (float)epoch[0];
    float g_wi = 0.1f   * expf(-0.1f  * e);
    float g_w  = 0.002f * expf(-0.008f* e);
    float g_a  = 0.001f * expf(-0.008f* e);
    float g_k  = 0.1f   * expf(-0.008f* e);
    float ek = 0.f;
    for (int j = 0; j < 23; j++) ek += sqrtf(ws[ACC_OFF + 4 + j]);
    out[0] = ws[ACC_OFF+0] + g_wi*ws[ACC_OFF+1] + g_w*ws[ACC_OFF+2]
           + g_a*ws[ACC_OFF+3] + g_k*ek;
  }
}

extern "C" void kernel_launch(void* const* d_in, const int* in_sizes, int n_in,
                              void* d_out, int out_size, void* d_ws, size_t ws_size,
                              hipStream_t stream) {
  const float* V     = (const float*)d_in[0];
  const float* T     = (const float*)d_in[1];
  const float* J     = (const float*)d_in[2];
  const float* theta = (const float*)d_in[3];
  const float* Wp    = (const float*)d_in[4];
  const float* Wi    = (const float*)d_in[5];
  const float* A     = (const float*)d_in[6];
  const float* K     = (const float*)d_in[7];
  const float* b2    = (const float*)d_in[8];
  const int*   epoch = (const int*)d_in[9];
  float* out = (float*)d_out;
  float* ws  = (float*)d_ws;
  // needs 47.2 MB workspace (TP_OFF + 200*20670 floats)

  hipLaunchKernelGGL(kInit, dim3(391),      dim3(256), 0, stream, ws);
  hipLaunchKernelGGL(kA,    dim3(PREG),     dim3(64),  0, stream, J, theta, b2, ws);
  hipLaunchKernelGGL(kKW,   dim3(41, 391),  dim3(256), 0, stream, K, A, ws);
  hipLaunchKernelGGL(kB,    dim3(646),      dim3(256), 0, stream, ws);
  hipLaunchKernelGGL(kC,    dim3(27, PREG), dim3(256), 0, stream, V, T, Wp, ws, out);
  hipLaunchKernelGGL(kD,    dim3(27),       dim3(256), 0, stream, Wp, Wi, A, ws);
  hipLaunchKernelGGL(kF,    dim3(1),        dim3(64),  0, stream, epoch, ws, out);
}

// Round 2
// 298.487 us; speedup vs baseline: 2.3517x; 2.3517x over previous
//
#include <hip/hip_runtime.h>
#include <math.h>

// Problem constants
#define KJ 24
#define NV 6890
#define PREG 200
#define M_TOT (NV*3)          // 20670
#define KDIM 391              // 23*17
#define QMT_STRIDE 256        // qm^T [k][p]
#define PTILE 20              // p per block in kB (200/20 = 10 tiles)
#define MT 512                // m per block in kB (2 floats per lane)

// Workspace layout (float offsets). Total = 4,458,112 floats = 17.8 MB.
#define ACC_OFF 0                               // [1]=EWi [2]=EW [3]=EA [4..26]=EK[j]
#define ED_OFF  32                              // 1024 spread slots for E_D
#define G_OFF   1056                            // G' : 200 x 24 x 12  (16B aligned)
#define QMT_OFF (G_OFF + PREG*288)              // 58,656 : qm^T 391 x 256
#define WT_OFF  (QMT_OFF + KDIM*QMT_STRIDE)     // 158,752 : W_change^T 24 x 6890
#define TP_OFF  (WT_OFF + 24*NV)                // 324,112 : T_p 200 x 20670 (p-major)

__constant__ int c_PARENT[24] = {0,0,0,0,1,2,3,4,5,6,7,8,9,9,9,12,13,14,16,17,18,19,20,21};
__constant__ int c_LEN[24]    = {4,3,3,3,3,3,3,3,3,2,2,2,4,3,3,2,3,3,3,3,3,3,2,2};
__constant__ int c_NBR[24][4] = {
  {0,1,2,3},{0,1,4,0},{0,2,5,0},{0,3,6,0},{1,4,7,0},{2,5,8,0},{3,6,9,0},{4,7,10,0},
  {5,8,11,0},{6,9,0,0},{7,10,0,0},{8,11,0,0},{12,13,14,15},{12,13,16,0},{12,14,17,0},
  {12,15,0,0},{13,16,18,0},{14,17,19,0},{16,18,20,0},{17,19,21,0},{18,20,22,0},
  {19,21,23,0},{20,22,0,0},{21,23,0,0}};

__device__ __forceinline__ float waveReduce(float v) {
  #pragma unroll
  for (int off = 32; off > 0; off >>= 1) v += __shfl_down(v, off, 64);
  return v;
}

// ---- init: zero accumulators + E_D slots ----
__global__ __launch_bounds__(1024) void kInit(float* __restrict__ ws) {
  int i = threadIdx.x;                 // 1 block x 1024
  ws[ED_OFF + i] = 0.f;
  if (i < 32) ws[ACC_OFF + i] = 0.f;
}

// ---- kernel A: per-p pose math -> G' (3x4 per joint) and qm^T ----
__global__ __launch_bounds__(64) void kA(const float* __restrict__ J,
                                         const float* __restrict__ theta,
                                         const float* __restrict__ beta2,
                                         float* __restrict__ ws) {
  int p = blockIdx.x, t = threadIdx.x;
  __shared__ float Gl[24][12];
  __shared__ float Gg[24][12];
  __shared__ float q[24][4];
  if (t < 24) {
    float x = theta[p*72 + 3*t + 0];
    float y = theta[p*72 + 3*t + 1];
    float z = theta[p*72 + 3*t + 2];
    float n2 = x*x + y*y + z*z;
    float ang = fmaxf(sqrtf(n2), 1e-8f);
    float ia = 1.f/ang;
    float ax = x*ia, ay = y*ia, az = z*ia;
    float c = cosf(ang), s = sinf(ang), C = 1.f - c;
    float jx = J[p*72+3*t], jy = J[p*72+3*t+1], jz = J[p*72+3*t+2];
    float tx = jx, ty = jy, tz = jz;
    if (t > 0) {
      int par = c_PARENT[t];
      tx -= J[p*72+3*par]; ty -= J[p*72+3*par+1]; tz -= J[p*72+3*par+2];
    }
    Gl[t][0]=c+C*ax*ax;   Gl[t][1]=C*ax*ay-s*az; Gl[t][2]=C*ax*az+s*ay; Gl[t][3]=tx;
    Gl[t][4]=C*ax*ay+s*az;Gl[t][5]=c+C*ay*ay;    Gl[t][6]=C*ay*az-s*ax; Gl[t][7]=ty;
    Gl[t][8]=C*ax*az-s*ay;Gl[t][9]=C*ay*az+s*ax; Gl[t][10]=c+C*az*az;   Gl[t][11]=tz;
    float ang2 = sqrtf(fmaxf(n2, 1e-16f));
    float inv2 = 1.f/ang2;
    float s2 = sinf(0.5f*ang2);
    q[t][0] = x*inv2*s2; q[t][1] = y*inv2*s2; q[t][2] = z*inv2*s2;
    q[t][3] = cosf(0.5f*ang2) - 1.f;
  }
  __syncthreads();
  if (t == 0) {  // sequential kinematic chain (parent[i] < i)
    #pragma unroll
    for (int i2 = 0; i2 < 12; i2++) Gg[0][i2] = Gl[0][i2];
    for (int i = 1; i < 24; i++) {
      int par = c_PARENT[i];
      for (int r = 0; r < 3; r++) {
        for (int c2 = 0; c2 < 4; c2++) {
          float v = Gg[par][r*4+0]*Gl[i][0+c2] + Gg[par][r*4+1]*Gl[i][4+c2]
                  + Gg[par][r*4+2]*Gl[i][8+c2];
          if (c2 == 3) v += Gg[par][r*4+3];
          Gg[i][r*4+c2] = v;
        }
      }
    }
  }
  __syncthreads();
  if (t < 24) {
    float jx = J[p*72+3*t], jy = J[p*72+3*t+1], jz = J[p*72+3*t+2];
    float* gp = ws + G_OFF + p*288 + t*12;
    #pragma unroll
    for (int r = 0; r < 3; r++) {
      float off = Gg[t][r*4+0]*jx + Gg[t][r*4+1]*jy + Gg[t][r*4+2]*jz;
      Gg[t][r*4+3] -= off;
    }
    #pragma unroll
    for (int i2 = 0; i2 < 12; i2++) gp[i2] = Gg[t][i2];
  }
  __syncthreads();
  float b2 = beta2[0];
  for (int e = t; e < KDIM; e += 64) {
    int j = e / 17, l = e - 17*j;
    int k = j + 1;
    float val = 0.f;
    if (l < 4*c_LEN[j] + 1) {            // SLICE_MASK row j
      if (l < 16) {
        int sidx = l >> 2, cc = l & 3;
        if (sidx < c_LEN[k]) val = q[c_NBR[k][sidx]][cc];
      }
      if (l == 4*c_LEN[k]) val += b2;    // BETA_POS row k
    }
    ws[QMT_OFF + e*QMT_STRIDE + p] = val;
  }
}

// ---- kernel D: W_change^T + E_Wi, E_W, E_A (runs BEFORE kC) ----
__global__ __launch_bounds__(256) void kD(const float* __restrict__ Wp,
                                          const float* __restrict__ Wi,
                                          const float* __restrict__ A,
                                          float* __restrict__ ws) {
  int n = blockIdx.x * 256 + threadIdx.x;
  float ewi = 0.f, ew = 0.f, ea = 0.f;
  if (n < NV) {
    float w[24]; float sum = 0.f;
    const float4* wp4 = (const float4*)(Wp + n*24);
    #pragma unroll
    for (int i = 0; i < 6; i++) {
      float4 v4 = wp4[i];
      w[4*i+0] = fmaxf(v4.x, 0.f); w[4*i+1] = fmaxf(v4.y, 0.f);
      w[4*i+2] = fmaxf(v4.z, 0.f); w[4*i+3] = fmaxf(v4.w, 0.f);
      sum += w[4*i+0]+w[4*i+1]+w[4*i+2]+w[4*i+3];
    }
    float inv = 1.f/(sum + 1e-8f);
    #pragma unroll
    for (int k = 0; k < 24; k++) {
      float wc = w[k]*inv;
      ws[WT_OFF + k*NV + n] = wc;       // transposed, coalesced store
      ew += fabsf(wc);
      float d = wc - Wi[n*24+k];
      ewi += d*d;
    }
  }
  int tot = 23*NV;
  int stride = gridDim.x * 256;
  for (int i = blockIdx.x*256 + threadIdx.x; i < tot; i += stride)
    ea += fabsf(A[i]);
  ewi = waveReduce(ewi); ew = waveReduce(ew); ea = waveReduce(ea);
  if ((threadIdx.x & 63) == 0) {
    atomicAdd(ws + ACC_OFF + 1, ewi);
    atomicAdd(ws + ACC_OFF + 2, ew);
    atomicAdd(ws + ACC_OFF + 3, ea);
  }
}

// ---- kernel EK: per-slice sum of K^2 for E_K ----
__global__ __launch_bounds__(256) void kEK(const float* __restrict__ K,
                                           float* __restrict__ ws) {
  int j = blockIdx.y;
  size_t base = (size_t)j * 17 * M_TOT;
  int tot = 17 * M_TOT;
  float sq = 0.f;
  int stride = gridDim.x * 256;
  for (int i = blockIdx.x*256 + threadIdx.x; i < tot; i += stride) {
    float v = K[base + i];
    sq = fmaf(v, v, sq);
  }
  sq = waveReduce(sq);
  __shared__ float tmp[4];
  int lane = threadIdx.x & 63, w = threadIdx.x >> 6;
  if (lane == 0) tmp[w] = sq;
  __syncthreads();
  if (threadIdx.x == 0)
    atomicAdd(ws + ACC_OFF + 4 + j, tmp[0]+tmp[1]+tmp[2]+tmp[3]);
}

// ---- kernel B: T_p(200 x 20670) = qm(200x391) @ (K ⊙ reluA)(391x20670)
//      lanes = m (coalesced float2 K loads), p-tile in regs, qm via s_load ----
__global__ __launch_bounds__(256) void kB(const float* __restrict__ K,
                                          const float* __restrict__ A,
                                          float* __restrict__ ws) {
  const float* __restrict__ qmT = ws + QMT_OFF;
  float* __restrict__ TP = ws + TP_OFF;
  int m = blockIdx.x * MT + threadIdx.x * 2;
  int p0 = blockIdx.y * PTILE;                 // wave-uniform
  bool valid = (m < M_TOT);                    // M_TOT even, m even -> m+1 ok too
  int mc = valid ? m : (M_TOT - 2);
  int n0 = mc / 3, n1 = (mc + 1) / 3;
  float acc0[PTILE], acc1[PTILE];
  #pragma unroll
  for (int pp = 0; pp < PTILE; pp++) { acc0[pp] = 0.f; acc1[pp] = 0.f; }
  for (int j = 0; j < 23; j++) {
    // burst-load the 17 K rows of this slice (17 loads in flight)
    float2 kreg[17];
    #pragma unroll
    for (int l = 0; l < 17; l++) {
      size_t off = (size_t)(j*17 + l) * M_TOT + mc;
      kreg[l] = *(const float2*)(K + off);
    }
    float a0 = fmaxf(A[j*NV + n0], 0.f);
    float a1 = fmaxf(A[j*NV + n1], 0.f);
    if (!valid) { a0 = 0.f; a1 = 0.f; }
    #pragma unroll
    for (int l = 0; l < 17; l++) { kreg[l].x *= a0; kreg[l].y *= a1; }
    #pragma unroll
    for (int l = 0; l < 17; l++) {
      const float* qrow = qmT + (size_t)(j*17 + l) * QMT_STRIDE + p0;  // uniform -> s_load
      #pragma unroll
      for (int pp = 0; pp < PTILE; pp++) {
        float qv = qrow[pp];
        acc0[pp] = fmaf(qv, kreg[l].x, acc0[pp]);
        acc1[pp] = fmaf(qv, kreg[l].y, acc1[pp]);
      }
    }
  }
  if (valid) {
    #pragma unroll
    for (int pp = 0; pp < PTILE; pp++) {
      float2 o; o.x = acc0[pp]; o.y = acc1[pp];
      *(float2*)(TP + (size_t)(p0 + pp) * M_TOT + m) = o;
    }
  }
}

// ---- kernel C: skinning + verts + E_D (G' in LDS, Wt coalesced, spread atomics) ----
__global__ __launch_bounds__(256) void kC(const float* __restrict__ V,
                                          const float* __restrict__ T,
                                          float* __restrict__ ws,
                                          float* __restrict__ out) {
  int p = blockIdx.y;
  int n = blockIdx.x * 256 + threadIdx.x;
  __shared__ float Gs[288];
  __shared__ float tmp[4];
  if (threadIdx.x < 72)
    ((float4*)Gs)[threadIdx.x] = ((const float4*)(ws + G_OFF + p*288))[threadIdx.x];
  __syncthreads();
  float ed = 0.f;
  if (n < NV) {
    const float* Wt = ws + WT_OFF;
    float M[12];
    #pragma unroll
    for (int i = 0; i < 12; i++) M[i] = 0.f;
    #pragma unroll
    for (int k = 0; k < 24; k++) {
      float wc = Wt[k*NV + n];                       // coalesced
      float4 g0 = *(const float4*)(Gs + k*12 + 0);   // 48B-aligned LDS broadcast
      float4 g1 = *(const float4*)(Gs + k*12 + 4);
      float4 g2 = *(const float4*)(Gs + k*12 + 8);
      M[0] = fmaf(wc, g0.x, M[0]); M[1]  = fmaf(wc, g0.y, M[1]);
      M[2] = fmaf(wc, g0.z, M[2]); M[3]  = fmaf(wc, g0.w, M[3]);
      M[4] = fmaf(wc, g1.x, M[4]); M[5]  = fmaf(wc, g1.y, M[5]);
      M[6] = fmaf(wc, g1.z, M[6]); M[7]  = fmaf(wc, g1.w, M[7]);
      M[8] = fmaf(wc, g2.x, M[8]); M[9]  = fmaf(wc, g2.y, M[9]);
      M[10]= fmaf(wc, g2.z, M[10]);M[11] = fmaf(wc, g2.w, M[11]);
    }
    size_t base = (size_t)p*M_TOT + 3*n;
    float t0 = ws[TP_OFF + base+0] + T[base+0];
    float t1 = ws[TP_OFF + base+1] + T[base+1];
    float t2 = ws[TP_OFF + base+2] + T[base+2];
    float v0 = M[0]*t0 + M[1]*t1 + M[2]*t2  + M[3];
    float v1 = M[4]*t0 + M[5]*t1 + M[6]*t2  + M[7];
    float v2 = M[8]*t0 + M[9]*t1 + M[10]*t2 + M[11];
    out[1+base+0] = v0; out[1+base+1] = v1; out[1+base+2] = v2;
    float d0 = V[base+0]-v0, d1 = V[base+1]-v1, d2 = V[base+2]-v2;
    ed = d0*d0 + d1*d1 + d2*d2;
  }
  ed = waveReduce(ed);
  int lane = threadIdx.x & 63, w = threadIdx.x >> 6;
  if (lane == 0) tmp[w] = ed;
  __syncthreads();
  if (threadIdx.x == 0) {
    int bid = blockIdx.y * gridDim.x + blockIdx.x;
    atomicAdd(ws + ED_OFF + (bid & 1023), tmp[0]+tmp[1]+tmp[2]+tmp[3]);
  }
}

// ---- kernel F: reduce E_D slots + final energy combine ----
__global__ __launch_bounds__(256) void kF(const int* __restrict__ epoch,
                                          const float* __restrict__ ws,
                                          float* __restrict__ out) {
  __shared__ float s[4];
  int t = threadIdx.x;
  float v = 0.f;
  #pragma unroll
  for (int i = 0; i < 4; i++) v += ws[ED_OFF + t + i*256];
  v = waveReduce(v);
  if ((t & 63) == 0) s[t >> 6] = v;
  __syncthreads();
  if (t == 0) {
    float ed = s[0]+s[1]+s[2]+s[3];
    float e    = (float)epoch[0];
    float g_wi = 0.1f   * expf(-0.1f  * e);
    float g_w  = 0.002f * expf(-0.008f* e);
    float g_a  = 0.001f * expf(-0.008f* e);
    float g_k  = 0.1f   * expf(-0.008f* e);
    float ek = 0.f;
    for (int j = 0; j < 23; j++) ek += sqrtf(ws[ACC_OFF + 4 + j]);
    out[0] = ed + g_wi*ws[ACC_OFF+1] + g_w*ws[ACC_OFF+2]
           + g_a*ws[ACC_OFF+3] + g_k*ek;
  }
}

extern "C" void kernel_launch(void* const* d_in, const int* in_sizes, int n_in,
                              void* d_out, int out_size, void* d_ws, size_t ws_size,
                              hipStream_t stream) {
  const float* V     = (const float*)d_in[0];
  const float* T     = (const float*)d_in[1];
  const float* J     = (const float*)d_in[2];
  const float* theta = (const float*)d_in[3];
  const float* Wp    = (const float*)d_in[4];
  const float* Wi    = (const float*)d_in[5];
  const float* A     = (const float*)d_in[6];
  const float* K     = (const float*)d_in[7];
  const float* b2    = (const float*)d_in[8];
  const int*   epoch = (const int*)d_in[9];
  float* out = (float*)d_out;
  float* ws  = (float*)d_ws;
  // needs 17.8 MB workspace

  hipLaunchKernelGGL(kInit, dim3(1),        dim3(1024), 0, stream, ws);
  hipLaunchKernelGGL(kA,    dim3(PREG),     dim3(64),   0, stream, J, theta, b2, ws);
  hipLaunchKernelGGL(kD,    dim3(27),       dim3(256),  0, stream, Wp, Wi, A, ws);
  hipLaunchKernelGGL(kEK,   dim3(43, 23),   dim3(256),  0, stream, K, ws);
  hipLaunchKernelGGL(kB,    dim3(41, 10),   dim3(256),  0, stream, K, A, ws);
  hipLaunchKernelGGL(kC,    dim3(27, PREG), dim3(256),  0, stream, V, T, ws, out);
  hipLaunchKernelGGL(kF,    dim3(1),        dim3(256),  0, stream, epoch, ws, out);
}

// Round 3
// 289.667 us; speedup vs baseline: 2.4234x; 1.0304x over previous
//
#include <hip/hip_runtime.h>
#include <math.h>

// Problem constants
#define KJ 24
#define NV 6890
#define PREG 200
#define M_TOT (NV*3)          // 20670
#define KDIM 391              // 23*17
#define QMT_STRIDE 256        // qm^T [k][p], p padded to 256 (>=200 zeroed)
#define TP_STRIDE 20672       // TP row stride (2 pad cols)
#define MTILE 64              // m per block in kB
#define NMTILE 323            // 323*64 = 20672

// Workspace layout (float offsets). Total ~6.11M floats = 24.4 MB.
#define EDP_OFF 0                               // 5400 E_D block partials (kC)
#define EKP_OFF 5400                            // 23*323 E_K partials (kB)
#define WIP_OFF 12829                           // 27 E_Wi partials
#define EWP_OFF 12856                           // 27 E_W partials
#define EAP_OFF 12883                           // 27 E_A partials
#define G_OFF   12928                           // G' : 200 x 24 x 12 (16B aligned)
#define QMT_OFF (G_OFF + PREG*288)              // 70,528 : qm^T 391 x 256
#define WT_OFF  (QMT_OFF + KDIM*QMT_STRIDE)     // 170,624 : W_change^T 24 x 6890
#define RA_OFF  (WT_OFF + 24*NV)                // 335,984 : RA 23 x 20672 (pad=0)
#define TP_OFF  811440                          // T_p 256 x 20672 (p-major, 16B aligned)

__constant__ int c_PARENT[24] = {0,0,0,0,1,2,3,4,5,6,7,8,9,9,9,12,13,14,16,17,18,19,20,21};
__constant__ int c_DEPTH[24]  = {0,1,1,1,2,2,2,3,3,3,4,4,4,4,4,5,5,5,6,6,7,7,8,8};
__constant__ int c_LEN[24]    = {4,3,3,3,3,3,3,3,3,2,2,2,4,3,3,2,3,3,3,3,3,3,2,2};
__constant__ int c_NBR[24][4] = {
  {0,1,2,3},{0,1,4,0},{0,2,5,0},{0,3,6,0},{1,4,7,0},{2,5,8,0},{3,6,9,0},{4,7,10,0},
  {5,8,11,0},{6,9,0,0},{7,10,0,0},{8,11,0,0},{12,13,14,15},{12,13,16,0},{12,14,17,0},
  {12,15,0,0},{13,16,18,0},{14,17,19,0},{16,18,20,0},{17,19,21,0},{18,20,22,0},
  {19,21,23,0},{20,22,0,0},{21,23,0,0}};

__device__ __forceinline__ float waveReduce(float v) {
  #pragma unroll
  for (int off = 32; off > 0; off >>= 1) v += __shfl_down(v, off, 64);
  return v;
}

// ---- kPre: blocks 0..49 = pose math (4 p per block, 1 wave each);
//      blocks 50..76 = W_change^T + RA + E_Wi/E_W/E_A partials + qm^T pad zero ----
__global__ __launch_bounds__(256) void kPre(const float* __restrict__ J,
                                            const float* __restrict__ theta,
                                            const float* __restrict__ beta2,
                                            const float* __restrict__ Wp,
                                            const float* __restrict__ Wi,
                                            const float* __restrict__ A,
                                            float* __restrict__ ws) {
  int b = blockIdx.x;
  if (b < 50) {
    // ---------------- pose path: 4 p per block, wave w -> p = b*4+w ----------------
    __shared__ float Gl[4][24][12];
    __shared__ float Gg[4][24][12];
    __shared__ float q[4][24][4];
    int w = threadIdx.x >> 6, t = threadIdx.x & 63;
    int p = b*4 + w;
    if (t < 24) {
      float x = theta[p*72 + 3*t + 0];
      float y = theta[p*72 + 3*t + 1];
      float z = theta[p*72 + 3*t + 2];
      float n2 = x*x + y*y + z*z;
      float ang = fmaxf(sqrtf(n2), 1e-8f);
      float ia = 1.f/ang;
      float ax = x*ia, ay = y*ia, az = z*ia;
      float c = cosf(ang), s = sinf(ang), C = 1.f - c;
      float jx = J[p*72+3*t], jy = J[p*72+3*t+1], jz = J[p*72+3*t+2];
      float tx = jx, ty = jy, tz = jz;
      if (t > 0) {
        int par = c_PARENT[t];
        tx -= J[p*72+3*par]; ty -= J[p*72+3*par+1]; tz -= J[p*72+3*par+2];
      }
      Gl[w][t][0]=c+C*ax*ax;   Gl[w][t][1]=C*ax*ay-s*az; Gl[w][t][2]=C*ax*az+s*ay; Gl[w][t][3]=tx;
      Gl[w][t][4]=C*ax*ay+s*az;Gl[w][t][5]=c+C*ay*ay;    Gl[w][t][6]=C*ay*az-s*ax; Gl[w][t][7]=ty;
      Gl[w][t][8]=C*ax*az-s*ay;Gl[w][t][9]=C*ay*az+s*ax; Gl[w][t][10]=c+C*az*az;   Gl[w][t][11]=tz;
      float ang2 = sqrtf(fmaxf(n2, 1e-16f));
      float inv2 = 1.f/ang2;
      float s2 = sinf(0.5f*ang2);
      q[w][t][0] = x*inv2*s2; q[w][t][1] = y*inv2*s2; q[w][t][2] = z*inv2*s2;
      q[w][t][3] = cosf(0.5f*ang2) - 1.f;
    }
    __syncthreads();
    // kinematic chain, parallel by tree level (depth 0..8)
    for (int lev = 0; lev <= 8; lev++) {
      if (t < 24 && c_DEPTH[t] == lev) {
        if (lev == 0) {
          for (int i2 = 0; i2 < 12; i2++) Gg[w][0][i2] = Gl[w][0][i2];
        } else {
          int par = c_PARENT[t];
          for (int r = 0; r < 3; r++) {
            float g0 = Gg[w][par][r*4+0], g1 = Gg[w][par][r*4+1];
            float g2 = Gg[w][par][r*4+2], g3 = Gg[w][par][r*4+3];
            for (int c2 = 0; c2 < 4; c2++) {
              float v = g0*Gl[w][t][0+c2] + g1*Gl[w][t][4+c2] + g2*Gl[w][t][8+c2];
              if (c2 == 3) v += g3;
              Gg[w][t][r*4+c2] = v;
            }
          }
        }
      }
      __syncthreads();
    }
    if (t < 24) {
      float jx = J[p*72+3*t], jy = J[p*72+3*t+1], jz = J[p*72+3*t+2];
      float* gp = ws + G_OFF + p*288 + t*12;
      #pragma unroll
      for (int r = 0; r < 3; r++) {
        float off = Gg[w][t][r*4+0]*jx + Gg[w][t][r*4+1]*jy + Gg[w][t][r*4+2]*jz;
        Gg[w][t][r*4+3] -= off;
      }
      #pragma unroll
      for (int i2 = 0; i2 < 12; i2++) gp[i2] = Gg[w][t][i2];
    }
    __syncthreads();
    float b2 = beta2[0];
    for (int e = t; e < KDIM; e += 64) {
      int j = e / 17, l = e - 17*j;
      int k = j + 1;
      float val = 0.f;
      if (l < 4*c_LEN[j] + 1) {            // SLICE_MASK row j
        if (l < 16) {
          int sidx = l >> 2, cc = l & 3;
          if (sidx < c_LEN[k]) val = q[w][c_NBR[k][sidx]][cc];
        }
        if (l == 4*c_LEN[k]) val += b2;    // BETA_POS row k
      }
      ws[QMT_OFF + e*QMT_STRIDE + p] = val;
    }
  } else {
    // ---------------- weights / RA / small-energy path ----------------
    int d = b - 50;                        // 0..26
    int t = threadIdx.x;
    int n = d*256 + t;
    float ewi = 0.f, ew = 0.f, ea = 0.f;
    if (n < NV) {
      float wv[24]; float sum = 0.f;
      const float4* wp4 = (const float4*)(Wp + n*24);
      #pragma unroll
      for (int i = 0; i < 6; i++) {
        float4 v4 = wp4[i];
        wv[4*i+0] = fmaxf(v4.x, 0.f); wv[4*i+1] = fmaxf(v4.y, 0.f);
        wv[4*i+2] = fmaxf(v4.z, 0.f); wv[4*i+3] = fmaxf(v4.w, 0.f);
        sum += wv[4*i+0]+wv[4*i+1]+wv[4*i+2]+wv[4*i+3];
      }
      float inv = 1.f/(sum + 1e-8f);
      #pragma unroll
      for (int k = 0; k < 24; k++) {
        float wc = wv[k]*inv;
        ws[WT_OFF + k*NV + n] = wc;
        ew += fabsf(wc);
        float dd = wc - Wi[n*24+k];
        ewi += dd*dd;
      }
    }
    // E_A (grid-stride over these 27 blocks)
    for (int i = d*256 + t; i < 23*NV; i += 27*256) ea += fabsf(A[i]);
    // RA[j][m] = relu(A[j][m/3]) with 2 zero pad cols per row
    for (int i = d*256 + t; i < 23*TP_STRIDE; i += 27*256) {
      int j = i / TP_STRIDE, m = i - j*TP_STRIDE;
      float v = 0.f;
      if (m < M_TOT) v = fmaxf(A[j*NV + m/3], 0.f);
      ws[RA_OFF + i] = v;
    }
    // zero qm^T pad columns p=200..255 (391 rows x 56 cols)
    for (int i = d*256 + t; i < KDIM*56; i += 27*256) {
      int row = i / 56, col = i - row*56;
      ws[QMT_OFF + row*QMT_STRIDE + 200 + col] = 0.f;
    }
    // block partials
    __shared__ float red[3][4];
    int lane = t & 63, wv2 = t >> 6;
    ewi = waveReduce(ewi); ew = waveReduce(ew); ea = waveReduce(ea);
    if (lane == 0) { red[0][wv2] = ewi; red[1][wv2] = ew; red[2][wv2] = ea; }
    __syncthreads();
    if (t == 0) {
      ws[WIP_OFF + d] = red[0][0]+red[0][1]+red[0][2]+red[0][3];
      ws[EWP_OFF + d] = red[1][0]+red[1][1]+red[1][2]+red[1][3];
      ws[EAP_OFF + d] = red[2][0]+red[2][1]+red[2][2]+red[2][3];
    }
  }
}

// ---- kB: TP(256 x 20672) = qm_pad(256x391) @ (K ⊙ RA)(391x20672)
//      LDS-tiled register-blocked fp32 GEMM; E_K folded into staging ----
__global__ __launch_bounds__(256) void kB(const float* __restrict__ K,
                                          float* __restrict__ ws) {
  const int tid = threadIdx.x;
  const int bx = blockIdx.x;           // m-tile 0..322
  const int py = blockIdx.y;           // 0..1 (p half)
  const int m0 = bx * MTILE;
  const int p0 = py * 128;
  const int wave = tid >> 6, lane = tid & 63;
  const int tx = tid & 15, ty = tid >> 4;

  __shared__ float As[17][128];        // qm^T slice [l][p]
  __shared__ float Bs[17][64];         // (K*RA) slice [l][m]
  __shared__ float ekl[4][23];

  const float* __restrict__ qmT = ws + QMT_OFF;
  const float* __restrict__ RA  = ws + RA_OFF;
  float* __restrict__ TP = ws + TP_OFF;

  float acc[8][4];
  #pragma unroll
  for (int i = 0; i < 8; i++)
    #pragma unroll
    for (int j2 = 0; j2 < 4; j2++) acc[i][j2] = 0.f;

  float4 areg[3];
  float  breg[5];

  auto load_stage = [&](int s) {
    int kb = s * 17;
    #pragma unroll
    for (int i = 0; i < 3; i++) {
      int idx4 = tid + i*256;
      if (idx4 < 544) {                 // 17 rows x 32 float4
        int r = idx4 >> 5, c4 = idx4 & 31;
        areg[i] = *(const float4*)(qmT + (kb + r)*QMT_STRIDE + p0 + c4*4);
      }
    }
    float sq = 0.f;
    #pragma unroll
    for (int i = 0; i < 5; i++) {
      int idx = tid + i*256;
      if (idx < 1088) {                 // 17 rows x 64
        int r = idx >> 6, c = idx & 63;
        int m = m0 + c;
        int mc = m < M_TOT ? m : M_TOT - 1;
        float kv = K[(size_t)(kb + r)*M_TOT + mc];
        if (m < M_TOT) sq = fmaf(kv, kv, sq);
        breg[i] = kv * RA[s*TP_STRIDE + m];   // RA pad col = 0
      }
    }
    if (py == 0) {                      // E_K: raw K^2, counted once
      sq = waveReduce(sq);
      if (lane == 0) ekl[wave][s] = sq;
    }
  };
  auto write_stage = [&]() {
    #pragma unroll
    for (int i = 0; i < 3; i++) {
      int idx4 = tid + i*256;
      if (idx4 < 544) {
        int r = idx4 >> 5, c4 = idx4 & 31;
        *(float4*)(&As[r][c4*4]) = areg[i];
      }
    }
    #pragma unroll
    for (int i = 0; i < 5; i++) {
      int idx = tid + i*256;
      if (idx < 1088) Bs[idx >> 6][idx & 63] = breg[i];
    }
  };

  load_stage(0);
  for (int s = 0; s < 23; s++) {
    __syncthreads();                    // prior compute done with LDS
    write_stage();                      // regs of stage s -> LDS
    if (s + 1 < 23) load_stage(s + 1);  // prefetch overlaps compute(s)
    __syncthreads();                    // LDS visible
    #pragma unroll
    for (int k = 0; k < 17; k++) {
      float4 bv4 = *(const float4*)(&Bs[k][tx*4]);
      float4 a0  = *(const float4*)(&As[k][ty*8]);
      float4 a1  = *(const float4*)(&As[k][ty*8 + 4]);
      float av[8] = {a0.x,a0.y,a0.z,a0.w,a1.x,a1.y,a1.z,a1.w};
      float bv[4] = {bv4.x,bv4.y,bv4.z,bv4.w};
      #pragma unroll
      for (int i = 0; i < 8; i++)
        #pragma unroll
        for (int j2 = 0; j2 < 4; j2++)
          acc[i][j2] = fmaf(av[i], bv[j2], acc[i][j2]);
    }
  }
  // store C tile (rows p>=200 land in TP's pad rows; harmless)
  #pragma unroll
  for (int i = 0; i < 8; i++) {
    int p = p0 + ty*8 + i;
    float4 o; o.x = acc[i][0]; o.y = acc[i][1]; o.z = acc[i][2]; o.w = acc[i][3];
    *(float4*)(TP + (size_t)p*TP_STRIDE + m0 + tx*4) = o;
  }
  __syncthreads();
  if (py == 0 && tid < 23) {
    float s = ekl[0][tid] + ekl[1][tid] + ekl[2][tid] + ekl[3][tid];
    ws[EKP_OFF + tid*NMTILE + bx] = s;
  }
}

// ---- kC: skinning + verts + E_D block partials ----
__global__ __launch_bounds__(256) void kC(const float* __restrict__ V,
                                          const float* __restrict__ T,
                                          float* __restrict__ ws,
                                          float* __restrict__ out) {
  int p = blockIdx.y;
  int n = blockIdx.x * 256 + threadIdx.x;
  __shared__ float Gs[288];
  __shared__ float tmp[4];
  if (threadIdx.x < 72)
    ((float4*)Gs)[threadIdx.x] = ((const float4*)(ws + G_OFF + p*288))[threadIdx.x];
  __syncthreads();
  float ed = 0.f;
  if (n < NV) {
    const float* Wt = ws + WT_OFF;
    float M[12];
    #pragma unroll
    for (int i = 0; i < 12; i++) M[i] = 0.f;
    #pragma unroll
    for (int k = 0; k < 24; k++) {
      float wc = Wt[k*NV + n];                       // coalesced
      float4 g0 = *(const float4*)(Gs + k*12 + 0);   // LDS broadcast
      float4 g1 = *(const float4*)(Gs + k*12 + 4);
      float4 g2 = *(const float4*)(Gs + k*12 + 8);
      M[0] = fmaf(wc, g0.x, M[0]); M[1]  = fmaf(wc, g0.y, M[1]);
      M[2] = fmaf(wc, g0.z, M[2]); M[3]  = fmaf(wc, g0.w, M[3]);
      M[4] = fmaf(wc, g1.x, M[4]); M[5]  = fmaf(wc, g1.y, M[5]);
      M[6] = fmaf(wc, g1.z, M[6]); M[7]  = fmaf(wc, g1.w, M[7]);
      M[8] = fmaf(wc, g2.x, M[8]); M[9]  = fmaf(wc, g2.y, M[9]);
      M[10]= fmaf(wc, g2.z, M[10]);M[11] = fmaf(wc, g2.w, M[11]);
    }
    size_t base  = (size_t)p*M_TOT + 3*n;
    size_t base2 = (size_t)p*TP_STRIDE + 3*n;
    float t0 = ws[TP_OFF + base2+0] + T[base+0];
    float t1 = ws[TP_OFF + base2+1] + T[base+1];
    float t2 = ws[TP_OFF + base2+2] + T[base+2];
    float v0 = M[0]*t0 + M[1]*t1 + M[2]*t2  + M[3];
    float v1 = M[4]*t0 + M[5]*t1 + M[6]*t2  + M[7];
    float v2 = M[8]*t0 + M[9]*t1 + M[10]*t2 + M[11];
    out[1+base+0] = v0; out[1+base+1] = v1; out[1+base+2] = v2;
    float d0 = V[base+0]-v0, d1 = V[base+1]-v1, d2 = V[base+2]-v2;
    ed = d0*d0 + d1*d1 + d2*d2;
  }
  ed = waveReduce(ed);
  int lane = threadIdx.x & 63, w = threadIdx.x >> 6;
  if (lane == 0) tmp[w] = ed;
  __syncthreads();
  if (threadIdx.x == 0)
    ws[EDP_OFF + blockIdx.y*27 + blockIdx.x] = tmp[0]+tmp[1]+tmp[2]+tmp[3];
}

// ---- kF: reduce all partials + final energy combine ----
__global__ __launch_bounds__(256) void kF(const int* __restrict__ epoch,
                                          const float* __restrict__ ws,
                                          float* __restrict__ out) {
  __shared__ float sb[4];
  __shared__ float eks[24];
  int t = threadIdx.x, lane = t & 63, w = t >> 6;
  float ed = 0.f;
  for (int i = t; i < 5400; i += 256) ed += ws[EDP_OFF + i];
  ed = waveReduce(ed);
  if (lane == 0) sb[w] = ed;
  // E_K per-slice: wave w handles j = w*6 .. w*6+5
  for (int jj = 0; jj < 6; jj++) {
    int j = w*6 + jj;
    if (j < 23) {
      float s = 0.f;
      for (int i = lane; i < NMTILE; i += 64) s += ws[EKP_OFF + j*NMTILE + i];
      s = waveReduce(s);
      if (lane == 0) eks[j] = s;
    }
  }
  __syncthreads();
  if (t == 0) {
    float edt = sb[0]+sb[1]+sb[2]+sb[3];
    float ewi = 0.f, ew = 0.f, ea = 0.f;
    for (int i = 0; i < 27; i++) {
      ewi += ws[WIP_OFF + i]; ew += ws[EWP_OFF + i]; ea += ws[EAP_OFF + i];
    }
    float ek = 0.f;
    for (int j = 0; j < 23; j++) ek += sqrtf(eks[j]);
    float e    = (float)epoch[0];
    float g_wi = 0.1f   * expf(-0.1f  * e);
    float g_w  = 0.002f * expf(-0.008f* e);
    float g_a  = 0.001f * expf(-0.008f* e);
    float g_k  = 0.1f   * expf(-0.008f* e);
    out[0] = edt + g_wi*ewi + g_w*ew + g_a*ea + g_k*ek;
  }
}

extern "C" void kernel_launch(void* const* d_in, const int* in_sizes, int n_in,
                              void* d_out, int out_size, void* d_ws, size_t ws_size,
                              hipStream_t stream) {
  const float* V     = (const float*)d_in[0];
  const float* T     = (const float*)d_in[1];
  const float* J     = (const float*)d_in[2];
  const float* theta = (const float*)d_in[3];
  const float* Wp    = (const float*)d_in[4];
  const float* Wi    = (const float*)d_in[5];
  const float* A     = (const float*)d_in[6];
  const float* K     = (const float*)d_in[7];
  const float* b2    = (const float*)d_in[8];
  const int*   epoch = (const int*)d_in[9];
  float* out = (float*)d_out;
  float* ws  = (float*)d_ws;
  // needs ~24.4 MB workspace

  hipLaunchKernelGGL(kPre, dim3(77),         dim3(256), 0, stream,
                     J, theta, b2, Wp, Wi, A, ws);
  hipLaunchKernelGGL(kB,   dim3(NMTILE, 2),  dim3(256), 0, stream, K, ws);
  hipLaunchKernelGGL(kC,   dim3(27, PREG),   dim3(256), 0, stream, V, T, ws, out);
  hipLaunchKernelGGL(kF,   dim3(1),          dim3(256), 0, stream, epoch, ws, out);
}

// Round 4
// 227.909 us; speedup vs baseline: 3.0800x; 1.2710x over previous
//
#include <hip/hip_runtime.h>
#include <math.h>

// Problem constants
#define KJ 24
#define NV 6890
#define PREG 200
#define M_TOT (NV*3)          // 20670
#define KDIM 391              // 23*17
#define KPAD 416              // 13 chunks of 32
#define TP_STRIDE 20672       // TP/RA row stride (2 pad cols)
#define NMTILE 323            // m-tiles of 64: 323*64 = 20672

// Workspace layout (float offsets). Total 5,940,528 floats = 23.8 MB.
#define EDP_OFF 0                               // 1400 E_D partials (kC: 7 x 200)
#define EKP_OFF 1408                            // 23*323 E_K partials (kB)
#define WIP_OFF 8840                            // 27 E_Wi partials
#define EWP_OFF 8872                            // 27 E_W partials
#define EAP_OFF 8904                            // 27 E_A partials
#define G_OFF   8944                            // G' : 200 x 24 x 12 (16B aligned)
#define WT_OFF  (G_OFF + PREG*288)              // 66,544 - 24 x 6890 W_change^T... 
// NOTE: WT placed where RA was planned; recompute below
// Final layout:
//   G_OFF   8944  (+57600)  -> 66544
//   WT_OFF  66544 (+165360) -> 231904
//   RA_OFF  231904 (+475456) -> 707360
//   QBH_OFF (ushort) 2*707360 = 1414720 (+106496) -> 1521216
//   QBL_OFF (ushort) 1521216 (+106496) -> 1627712  (= float 813856)
//   TP_OFF  813856 (+256*20672 = 5292032) -> 6105888 floats = 24.4 MB
#undef WT_OFF
#define WT_OFF  66544
#define RA_OFF  231904
#define QBH_OFF_U 1414720
#define QBL_OFF_U 1521216
#define TP_OFF  813856

typedef __attribute__((ext_vector_type(8))) short short8;
typedef __attribute__((ext_vector_type(4))) float f32x4;

__constant__ int c_PARENT[24] = {0,0,0,0,1,2,3,4,5,6,7,8,9,9,9,12,13,14,16,17,18,19,20,21};
__constant__ int c_DEPTH[24]  = {0,1,1,1,2,2,2,3,3,3,4,4,4,4,4,5,5,5,6,6,7,7,8,8};
__constant__ int c_LEN[24]    = {4,3,3,3,3,3,3,3,3,2,2,2,4,3,3,2,3,3,3,3,3,3,2,2};
__constant__ int c_NBR[24][4] = {
  {0,1,2,3},{0,1,4,0},{0,2,5,0},{0,3,6,0},{1,4,7,0},{2,5,8,0},{3,6,9,0},{4,7,10,0},
  {5,8,11,0},{6,9,0,0},{7,10,0,0},{8,11,0,0},{12,13,14,15},{12,13,16,0},{12,14,17,0},
  {12,15,0,0},{13,16,18,0},{14,17,19,0},{16,18,20,0},{17,19,21,0},{18,20,22,0},
  {19,21,23,0},{20,22,0,0},{21,23,0,0}};

__device__ __forceinline__ float waveReduce(float v) {
  #pragma unroll
  for (int off = 32; off > 0; off >>= 1) v += __shfl_down(v, off, 64);
  return v;
}
__device__ __forceinline__ unsigned short f2bf(float x) {
  union { float f; unsigned u; } v; v.f = x;
  unsigned r = v.u + 0x7FFFu + ((v.u >> 16) & 1u);
  return (unsigned short)(r >> 16);
}
__device__ __forceinline__ float bf2f(unsigned short h) {
  union { unsigned u; float f; } v; v.u = ((unsigned)h) << 16; return v.f;
}

// ---- kPre: blocks 0..49 pose math (4 p/block) -> G' + qm bf16 hi/lo planes;
//      blocks 50..76: W_change^T, RA, E_Wi/E_W/E_A partials, pad zeroing ----
__global__ __launch_bounds__(256) void kPre(const float* __restrict__ J,
                                            const float* __restrict__ theta,
                                            const float* __restrict__ beta2,
                                            const float* __restrict__ Wp,
                                            const float* __restrict__ Wi,
                                            const float* __restrict__ A,
                                            float* __restrict__ ws) {
  unsigned short* qbh = (unsigned short*)ws + QBH_OFF_U;
  unsigned short* qbl = (unsigned short*)ws + QBL_OFF_U;
  int b = blockIdx.x;
  if (b < 50) {
    __shared__ float Gl[4][24][12];
    __shared__ float Gg[4][24][12];
    __shared__ float q[4][24][4];
    int w = threadIdx.x >> 6, t = threadIdx.x & 63;
    int p = b*4 + w;
    if (t < 24) {
      float x = theta[p*72 + 3*t + 0];
      float y = theta[p*72 + 3*t + 1];
      float z = theta[p*72 + 3*t + 2];
      float n2 = x*x + y*y + z*z;
      float ang = fmaxf(sqrtf(n2), 1e-8f);
      float ia = 1.f/ang;
      float ax = x*ia, ay = y*ia, az = z*ia;
      float c = cosf(ang), s = sinf(ang), C = 1.f - c;
      float jx = J[p*72+3*t], jy = J[p*72+3*t+1], jz = J[p*72+3*t+2];
      float tx = jx, ty = jy, tz = jz;
      if (t > 0) {
        int par = c_PARENT[t];
        tx -= J[p*72+3*par]; ty -= J[p*72+3*par+1]; tz -= J[p*72+3*par+2];
      }
      Gl[w][t][0]=c+C*ax*ax;   Gl[w][t][1]=C*ax*ay-s*az; Gl[w][t][2]=C*ax*az+s*ay; Gl[w][t][3]=tx;
      Gl[w][t][4]=C*ax*ay+s*az;Gl[w][t][5]=c+C*ay*ay;    Gl[w][t][6]=C*ay*az-s*ax; Gl[w][t][7]=ty;
      Gl[w][t][8]=C*ax*az-s*ay;Gl[w][t][9]=C*ay*az+s*ax; Gl[w][t][10]=c+C*az*az;   Gl[w][t][11]=tz;
      float ang2 = sqrtf(fmaxf(n2, 1e-16f));
      float inv2 = 1.f/ang2;
      float s2 = sinf(0.5f*ang2);
      q[w][t][0] = x*inv2*s2; q[w][t][1] = y*inv2*s2; q[w][t][2] = z*inv2*s2;
      q[w][t][3] = cosf(0.5f*ang2) - 1.f;
    }
    __syncthreads();
    for (int lev = 0; lev <= 8; lev++) {
      if (t < 24 && c_DEPTH[t] == lev) {
        if (lev == 0) {
          for (int i2 = 0; i2 < 12; i2++) Gg[w][0][i2] = Gl[w][0][i2];
        } else {
          int par = c_PARENT[t];
          for (int r = 0; r < 3; r++) {
            float g0 = Gg[w][par][r*4+0], g1 = Gg[w][par][r*4+1];
            float g2 = Gg[w][par][r*4+2], g3 = Gg[w][par][r*4+3];
            for (int c2 = 0; c2 < 4; c2++) {
              float v = g0*Gl[w][t][0+c2] + g1*Gl[w][t][4+c2] + g2*Gl[w][t][8+c2];
              if (c2 == 3) v += g3;
              Gg[w][t][r*4+c2] = v;
            }
          }
        }
      }
      __syncthreads();
    }
    if (t < 24) {
      float jx = J[p*72+3*t], jy = J[p*72+3*t+1], jz = J[p*72+3*t+2];
      float* gp = ws + G_OFF + p*288 + t*12;
      #pragma unroll
      for (int r = 0; r < 3; r++) {
        float off = Gg[w][t][r*4+0]*jx + Gg[w][t][r*4+1]*jy + Gg[w][t][r*4+2]*jz;
        Gg[w][t][r*4+3] -= off;
      }
      #pragma unroll
      for (int i2 = 0; i2 < 12; i2++) gp[i2] = Gg[w][t][i2];
    }
    __syncthreads();
    float b2 = beta2[0];
    for (int e = t; e < KDIM; e += 64) {
      int j = e / 17, l = e - 17*j;
      int k = j + 1;
      float val = 0.f;
      if (l < 4*c_LEN[j] + 1) {
        if (l < 16) {
          int sidx = l >> 2, cc = l & 3;
          if (sidx < c_LEN[k]) val = q[w][c_NBR[k][sidx]][cc];
        }
        if (l == 4*c_LEN[k]) val += b2;
      }
      unsigned short hi = f2bf(val);
      unsigned short lo = f2bf(val - bf2f(hi));
      qbh[p*KPAD + e] = hi;
      qbl[p*KPAD + e] = lo;
    }
    for (int e = KDIM + t; e < KPAD; e += 64) {   // k pad
      qbh[p*KPAD + e] = 0; qbl[p*KPAD + e] = 0;
    }
  } else {
    int d = b - 50;                        // 0..26
    int t = threadIdx.x;
    int n = d*256 + t;
    float ewi = 0.f, ew = 0.f, ea = 0.f;
    if (n < NV) {
      float wv[24]; float sum = 0.f;
      const float4* wp4 = (const float4*)(Wp + n*24);
      #pragma unroll
      for (int i = 0; i < 6; i++) {
        float4 v4 = wp4[i];
        wv[4*i+0] = fmaxf(v4.x, 0.f); wv[4*i+1] = fmaxf(v4.y, 0.f);
        wv[4*i+2] = fmaxf(v4.z, 0.f); wv[4*i+3] = fmaxf(v4.w, 0.f);
        sum += wv[4*i+0]+wv[4*i+1]+wv[4*i+2]+wv[4*i+3];
      }
      float inv = 1.f/(sum + 1e-8f);
      #pragma unroll
      for (int k = 0; k < 24; k++) {
        float wc = wv[k]*inv;
        ws[WT_OFF + k*NV + n] = wc;
        ew += fabsf(wc);
        float dd = wc - Wi[n*24+k];
        ewi += dd*dd;
      }
    }
    for (int i = d*256 + t; i < 23*NV; i += 27*256) ea += fabsf(A[i]);
    // RA[j][m] = relu(A[j][m/3]), pad cols 0
    for (int i = d*256 + t; i < 23*TP_STRIDE; i += 27*256) {
      int j = i / TP_STRIDE, m = i - j*TP_STRIDE;
      float v = 0.f;
      if (m < M_TOT) v = fmaxf(A[j*NV + m/3], 0.f);
      ws[RA_OFF + i] = v;
    }
    // zero qm bf16 pad rows p = 200..255
    for (int i = d*256 + t; i < 56*KPAD; i += 27*256) {
      qbh[200*KPAD + i] = 0; qbl[200*KPAD + i] = 0;
    }
    __shared__ float red[3][4];
    int lane = t & 63, wv2 = t >> 6;
    ewi = waveReduce(ewi); ew = waveReduce(ew); ea = waveReduce(ea);
    if (lane == 0) { red[0][wv2] = ewi; red[1][wv2] = ew; red[2][wv2] = ea; }
    __syncthreads();
    if (t == 0) {
      ws[WIP_OFF + d] = red[0][0]+red[0][1]+red[0][2]+red[0][3];
      ws[EWP_OFF + d] = red[1][0]+red[1][1]+red[1][2]+red[1][3];
      ws[EAP_OFF + d] = red[2][0]+red[2][1]+red[2][2]+red[2][3];
    }
  }
}

// ---- kB: TP(256 x 20672) = qm(256x391) @ (K ⊙ RA)(391x20672)
//      split-bf16 MFMA (hi/lo, 3 terms): fp32-accurate, LDS-light.
//      Block: 256 thr = 4 waves; tile 128p x 64m; grid (323 m-tiles, 2 p-tiles).
//      E_K (raw K^2 per slice) folded into staging on p-tile 0. ----
__global__ __launch_bounds__(256) void kB(const float* __restrict__ K,
                                          float* __restrict__ ws) {
  __shared__ unsigned short Bh[64*32];
  __shared__ unsigned short Bl[64*32];
  __shared__ float ek[23];
  const unsigned short* qbh = (const unsigned short*)ws + QBH_OFF_U;
  const unsigned short* qbl = (const unsigned short*)ws + QBL_OFF_U;
  float* __restrict__ TP = ws + TP_OFF;

  const int tid = threadIdx.x;
  const int bx = blockIdx.x;                 // m-tile
  const int py = blockIdx.y;                 // p-tile (0/1)
  const int m0 = bx * 64;
  const int w = tid >> 6, lane = tid & 63;
  const int r = lane & 15, qd = lane >> 4;   // MFMA row/col and quad
  const int pbase = py*128 + w*32;
  // staging mapping: c4 (m quad), pr (k row-pair)
  const int c4 = tid & 15, pr = tid >> 4;

  if (tid < 23) ek[tid] = 0.f;
  __syncthreads();

  f32x4 acc[2][4];
  #pragma unroll
  for (int h = 0; h < 2; h++)
    #pragma unroll
    for (int f = 0; f < 4; f++) acc[h][f] = (f32x4){0.f,0.f,0.f,0.f};

  // per-lane A offsets (ushort units)
  const int aoff0 = (pbase + r) * KPAD + qd * 8;
  const int aoff1 = aoff0 + 16 * KPAD;

  for (int ks = 0; ks < 13; ks++) {
    if (ks) __syncthreads();
    // ---- stage B chunk: rows kg = ks*32 + {2pr, 2pr+1}, m = m0 + 4c4 .. +3 ----
    {
      int mm = m0 + 4*c4;
      int kg0 = ks*32 + 2*pr, kg1 = kg0 + 1;
      float ka[4] = {0,0,0,0}, kb[4] = {0,0,0,0};
      float wa[4] = {0,0,0,0}, wb[4] = {0,0,0,0};
      float sq0 = 0.f, sq1 = 0.f;
      if (kg0 < KDIM) {
        int j = kg0 / 17;
        const float* kr = K + (size_t)kg0*M_TOT + mm;
        if (mm + 3 < M_TOT) {
          float2 x = *(const float2*)kr; float2 y = *(const float2*)(kr+2);
          ka[0]=x.x; ka[1]=x.y; ka[2]=y.x; ka[3]=y.y;
        } else {
          #pragma unroll
          for (int i = 0; i < 4; i++) if (mm+i < M_TOT) ka[i] = kr[i];
        }
        const float* rr = ws + RA_OFF + (size_t)j*TP_STRIDE + mm;
        float4 ra = *(const float4*)rr;
        wa[0]=ka[0]*ra.x; wa[1]=ka[1]*ra.y; wa[2]=ka[2]*ra.z; wa[3]=ka[3]*ra.w;
        sq0 = ka[0]*ka[0]+ka[1]*ka[1]+ka[2]*ka[2]+ka[3]*ka[3];
      }
      if (kg1 < KDIM) {
        int j = kg1 / 17;
        const float* kr = K + (size_t)kg1*M_TOT + mm;
        if (mm + 3 < M_TOT) {
          float2 x = *(const float2*)kr; float2 y = *(const float2*)(kr+2);
          kb[0]=x.x; kb[1]=x.y; kb[2]=y.x; kb[3]=y.y;
        } else {
          #pragma unroll
          for (int i = 0; i < 4; i++) if (mm+i < M_TOT) kb[i] = kr[i];
        }
        const float* rr = ws + RA_OFF + (size_t)j*TP_STRIDE + mm;
        float4 ra = *(const float4*)rr;
        wb[0]=kb[0]*ra.x; wb[1]=kb[1]*ra.y; wb[2]=kb[2]*ra.z; wb[3]=kb[3]*ra.w;
        sq1 = kb[0]*kb[0]+kb[1]*kb[1]+kb[2]*kb[2]+kb[3]*kb[3];
      }
      #pragma unroll
      for (int i = 0; i < 4; i++) {
        unsigned short h0 = f2bf(wa[i]); unsigned short l0 = f2bf(wa[i] - bf2f(h0));
        unsigned short h1 = f2bf(wb[i]); unsigned short l1 = f2bf(wb[i] - bf2f(h1));
        int mi = 4*c4 + i;
        int physdw = (pr + 4*(c4 & 3)) & 15;        // bank swizzle
        *(unsigned*)&Bh[mi*32 + physdw*2] = (unsigned)h0 | ((unsigned)h1 << 16);
        *(unsigned*)&Bl[mi*32 + physdw*2] = (unsigned)l0 | ((unsigned)l1 << 16);
      }
      if (py == 0) {   // E_K: reduce over c4 subgroup (16 lanes share rows)
        #pragma unroll
        for (int off = 1; off <= 8; off <<= 1) {
          sq0 += __shfl_xor(sq0, off, 64);
          sq1 += __shfl_xor(sq1, off, 64);
        }
        if ((lane & 15) == 0) {
          if (kg0 < KDIM) atomicAdd(&ek[kg0/17], sq0);
          if (kg1 < KDIM) atomicAdd(&ek[kg1/17], sq1);
        }
      }
    }
    __syncthreads();
    // ---- A frags direct from global (L2-hot), B frags from LDS, 24 MFMA ----
    {
      int kso = ks * 32;
      short8 ah0 = *(const short8*)(qbh + aoff0 + kso);
      short8 ah1 = *(const short8*)(qbh + aoff1 + kso);
      short8 al0 = *(const short8*)(qbl + aoff0 + kso);
      short8 al1 = *(const short8*)(qbl + aoff1 + kso);
      short8 bh[4], bl[4];
      const int rotdw = 4*((r >> 2) & 3);
      #pragma unroll
      for (int f = 0; f < 4; f++) {
        int m = f*16 + r;
        int physdw = (4*qd + rotdw) & 15;
        bh[f] = *(const short8*)(&Bh[m*32 + physdw*2]);
        bl[f] = *(const short8*)(&Bl[m*32 + physdw*2]);
      }
      #pragma unroll
      for (int f = 0; f < 4; f++) {
        acc[0][f] = __builtin_amdgcn_mfma_f32_16x16x32_bf16(ah0, bh[f], acc[0][f], 0, 0, 0);
        acc[1][f] = __builtin_amdgcn_mfma_f32_16x16x32_bf16(ah1, bh[f], acc[1][f], 0, 0, 0);
      }
      #pragma unroll
      for (int f = 0; f < 4; f++) {
        acc[0][f] = __builtin_amdgcn_mfma_f32_16x16x32_bf16(ah0, bl[f], acc[0][f], 0, 0, 0);
        acc[1][f] = __builtin_amdgcn_mfma_f32_16x16x32_bf16(ah1, bl[f], acc[1][f], 0, 0, 0);
      }
      #pragma unroll
      for (int f = 0; f < 4; f++) {
        acc[0][f] = __builtin_amdgcn_mfma_f32_16x16x32_bf16(al0, bh[f], acc[0][f], 0, 0, 0);
        acc[1][f] = __builtin_amdgcn_mfma_f32_16x16x32_bf16(al1, bh[f], acc[1][f], 0, 0, 0);
      }
    }
  }
  // ---- epilogue: C layout col=lane&15 (m), row=quad*4+reg (p) ----
  #pragma unroll
  for (int h = 0; h < 2; h++)
    #pragma unroll
    for (int f = 0; f < 4; f++)
      #pragma unroll
      for (int g = 0; g < 4; g++) {
        int p = pbase + h*16 + qd*4 + g;
        TP[(size_t)p*TP_STRIDE + m0 + f*16 + r] = acc[h][f][g];
      }
  __syncthreads();
  if (py == 0 && tid < 23)
    ws[EKP_OFF + tid*NMTILE + bx] = ek[tid];
}

// ---- kC: skinning + verts + E_D partials. 4 vertices/thread. ----
__global__ __launch_bounds__(256) void kC(const float* __restrict__ V,
                                          const float* __restrict__ T,
                                          float* __restrict__ ws,
                                          float* __restrict__ out) {
  int p = blockIdx.y;
  int gt = blockIdx.x*256 + threadIdx.x;
  int n0 = gt*4;
  __shared__ float Gs[288];
  __shared__ float tmp[4];
  if (threadIdx.x < 72)
    ((float4*)Gs)[threadIdx.x] = ((const float4*)(ws + G_OFF + p*288))[threadIdx.x];
  __syncthreads();
  float ed = 0.f;
  if (n0 < NV) {
    float M[4][12];
    #pragma unroll
    for (int v = 0; v < 4; v++)
      #pragma unroll
      for (int i = 0; i < 12; i++) M[v][i] = 0.f;
    const float* Wt = ws + WT_OFF;
    #pragma unroll
    for (int k = 0; k < 24; k++) {
      const float* wr = Wt + k*NV + n0;
      float2 a = *(const float2*)(wr);
      float2 b = *(const float2*)(wr + 2);
      float wv[4] = {a.x, a.y, b.x, b.y};
      float4 g0 = *(const float4*)(Gs + k*12 + 0);
      float4 g1 = *(const float4*)(Gs + k*12 + 4);
      float4 g2 = *(const float4*)(Gs + k*12 + 8);
      #pragma unroll
      for (int v = 0; v < 4; v++) {
        float wc = wv[v];
        M[v][0] = fmaf(wc, g0.x, M[v][0]); M[v][1]  = fmaf(wc, g0.y, M[v][1]);
        M[v][2] = fmaf(wc, g0.z, M[v][2]); M[v][3]  = fmaf(wc, g0.w, M[v][3]);
        M[v][4] = fmaf(wc, g1.x, M[v][4]); M[v][5]  = fmaf(wc, g1.y, M[v][5]);
        M[v][6] = fmaf(wc, g1.z, M[v][6]); M[v][7]  = fmaf(wc, g1.w, M[v][7]);
        M[v][8] = fmaf(wc, g2.x, M[v][8]); M[v][9]  = fmaf(wc, g2.y, M[v][9]);
        M[v][10]= fmaf(wc, g2.z, M[v][10]);M[v][11] = fmaf(wc, g2.w, M[v][11]);
      }
    }
    size_t tb = (size_t)p*M_TOT + 3*n0;       // T, V, out base
    size_t pb = (size_t)p*TP_STRIDE + 3*n0;   // TP base
    float th[12];
    if (n0 + 3 < NV) {                        // fast path: 12 elements valid
      float4 q0 = *(const float4*)(ws + TP_OFF + pb);
      float4 q1 = *(const float4*)(ws + TP_OFF + pb + 4);
      float4 q2 = *(const float4*)(ws + TP_OFF + pb + 8);
      float tpv[12] = {q0.x,q0.y,q0.z,q0.w,q1.x,q1.y,q1.z,q1.w,q2.x,q2.y,q2.z,q2.w};
      #pragma unroll
      for (int i = 0; i < 6; i++) {
        float2 t2 = *(const float2*)(T + tb + 2*i);
        th[2*i] = tpv[2*i] + t2.x; th[2*i+1] = tpv[2*i+1] + t2.y;
      }
      #pragma unroll
      for (int v = 0; v < 4; v++) {
        float t0 = th[3*v], t1 = th[3*v+1], t2 = th[3*v+2];
        float v0 = M[v][0]*t0 + M[v][1]*t1 + M[v][2]*t2  + M[v][3];
        float v1 = M[v][4]*t0 + M[v][5]*t1 + M[v][6]*t2  + M[v][7];
        float v2 = M[v][8]*t0 + M[v][9]*t1 + M[v][10]*t2 + M[v][11];
        out[1+tb+3*v+0] = v0; out[1+tb+3*v+1] = v1; out[1+tb+3*v+2] = v2;
        float d0 = V[tb+3*v]-v0, d1 = V[tb+3*v+1]-v1, d2 = V[tb+3*v+2]-v2;
        ed += d0*d0 + d1*d1 + d2*d2;
      }
    } else {                                  // tail: guard per vertex
      #pragma unroll
      for (int v = 0; v < 4; v++) {
        if (n0 + v < NV) {
          float t0 = ws[TP_OFF + pb + 3*v]   + T[tb + 3*v];
          float t1 = ws[TP_OFF + pb + 3*v+1] + T[tb + 3*v+1];
          float t2 = ws[TP_OFF + pb + 3*v+2] + T[tb + 3*v+2];
          float v0 = M[v][0]*t0 + M[v][1]*t1 + M[v][2]*t2  + M[v][3];
          float v1 = M[v][4]*t0 + M[v][5]*t1 + M[v][6]*t2  + M[v][7];
          float v2 = M[v][8]*t0 + M[v][9]*t1 + M[v][10]*t2 + M[v][11];
          out[1+tb+3*v+0] = v0; out[1+tb+3*v+1] = v1; out[1+tb+3*v+2] = v2;
          float d0 = V[tb+3*v]-v0, d1 = V[tb+3*v+1]-v1, d2 = V[tb+3*v+2]-v2;
          ed += d0*d0 + d1*d1 + d2*d2;
        }
      }
    }
  }
  ed = waveReduce(ed);
  int lane = threadIdx.x & 63, w = threadIdx.x >> 6;
  if (lane == 0) tmp[w] = ed;
  __syncthreads();
  if (threadIdx.x == 0)
    ws[EDP_OFF + blockIdx.y*7 + blockIdx.x] = tmp[0]+tmp[1]+tmp[2]+tmp[3];
}

// ---- kF: reduce all partials + final energy ----
__global__ __launch_bounds__(256) void kF(const int* __restrict__ epoch,
                                          const float* __restrict__ ws,
                                          float* __restrict__ out) {
  __shared__ float sb[4];
  __shared__ float eks[24];
  int t = threadIdx.x, lane = t & 63, w = t >> 6;
  float ed = 0.f;
  for (int i = t; i < 1400; i += 256) ed += ws[EDP_OFF + i];
  ed = waveReduce(ed);
  if (lane == 0) sb[w] = ed;
  for (int jj = 0; jj < 6; jj++) {
    int j = w*6 + jj;
    if (j < 23) {
      float s = 0.f;
      for (int i = lane; i < NMTILE; i += 64) s += ws[EKP_OFF + j*NMTILE + i];
      s = waveReduce(s);
      if (lane == 0) eks[j] = s;
    }
  }
  __syncthreads();
  if (t == 0) {
    float edt = sb[0]+sb[1]+sb[2]+sb[3];
    float ewi = 0.f, ew = 0.f, ea = 0.f;
    for (int i = 0; i < 27; i++) {
      ewi += ws[WIP_OFF + i]; ew += ws[EWP_OFF + i]; ea += ws[EAP_OFF + i];
    }
    float ek = 0.f;
    for (int j = 0; j < 23; j++) ek += sqrtf(eks[j]);
    float e    = (float)epoch[0];
    float g_wi = 0.1f   * expf(-0.1f  * e);
    float g_w  = 0.002f * expf(-0.008f* e);
    float g_a  = 0.001f * expf(-0.008f* e);
    float g_k  = 0.1f   * expf(-0.008f* e);
    out[0] = edt + g_wi*ewi + g_w*ew + g_a*ea + g_k*ek;
  }
}

extern "C" void kernel_launch(void* const* d_in, const int* in_sizes, int n_in,
                              void* d_out, int out_size, void* d_ws, size_t ws_size,
                              hipStream_t stream) {
  const float* V     = (const float*)d_in[0];
  const float* T     = (const float*)d_in[1];
  const float* J     = (const float*)d_in[2];
  const float* theta = (const float*)d_in[3];
  const float* Wp    = (const float*)d_in[4];
  const float* Wi    = (const float*)d_in[5];
  const float* A     = (const float*)d_in[6];
  const float* K     = (const float*)d_in[7];
  const float* b2    = (const float*)d_in[8];
  const int*   epoch = (const int*)d_in[9];
  float* out = (float*)d_out;
  float* ws  = (float*)d_ws;
  // needs ~24.5 MB workspace

  hipLaunchKernelGGL(kPre, dim3(77),         dim3(256), 0, stream,
                     J, theta, b2, Wp, Wi, A, ws);
  hipLaunchKernelGGL(kB,   dim3(NMTILE, 2),  dim3(256), 0, stream, K, ws);
  hipLaunchKernelGGL(kC,   dim3(7, PREG),    dim3(256), 0, stream, V, T, ws, out);
  hipLaunchKernelGGL(kF,   dim3(1),          dim3(256), 0, stream, epoch, ws, out);
}

// Round 5
// 203.798 us; speedup vs baseline: 3.4444x; 1.1183x over previous
//
#include <hip/hip_runtime.h>
#include <math.h>

// Problem constants
#define KJ 24
#define NV 6890
#define PREG 200
#define M_TOT (NV*3)          // 20670
#define KDIM 391              // 23*17
#define KPAD 416              // 13 chunks of 32
#define TP_STRIDE 20672       // TP/RA row stride (2 pad cols)
#define NMTILE 323            // m-tiles of 64: 323*64 = 20672

// Workspace layout (float offsets). Total 6,107,328 floats = 24.43 MB.
#define EDP_OFF 0                // 2800 E_D partials (kC grid 14 x 200)
#define EKP_OFF 2816            // 23*323 = 7429 E_K partials (kB)
#define WIP_OFF 10248           // 27 E_Wi partials
#define EWP_OFF 10280           // 27 E_W partials
#define EAP_OFF 10312           // 27 E_A partials
#define RED_OFF 10344           // 32: [0..22]=EKsum_j [23]=ED [24]=EWi [25]=EW [26]=EA
#define G_OFF   10384           // G' : 200 x 24 x 12 (16B aligned)
#define WT_OFF  67984           // W_change^T 24 x 6890
#define RA_OFF  233344          // RA 23 x 20672 (pad cols 0)
#define QBH_OFF_U 1417600       // ushort offset: qm hi bf16, 256 x 416
#define QBL_OFF_U 1524096       // ushort offset: qm lo bf16, 256 x 416
#define TP_OFF  815296          // T_p 256 x 20672 (p-major)

typedef __attribute__((ext_vector_type(8))) short short8;
typedef __attribute__((ext_vector_type(4))) float f32x4;

__constant__ int c_PARENT[24] = {0,0,0,0,1,2,3,4,5,6,7,8,9,9,9,12,13,14,16,17,18,19,20,21};
__constant__ int c_DEPTH[24]  = {0,1,1,1,2,2,2,3,3,3,4,4,4,4,4,5,5,5,6,6,7,7,8,8};
__constant__ int c_LEN[24]    = {4,3,3,3,3,3,3,3,3,2,2,2,4,3,3,2,3,3,3,3,3,3,2,2};
__constant__ int c_NBR[24][4] = {
  {0,1,2,3},{0,1,4,0},{0,2,5,0},{0,3,6,0},{1,4,7,0},{2,5,8,0},{3,6,9,0},{4,7,10,0},
  {5,8,11,0},{6,9,0,0},{7,10,0,0},{8,11,0,0},{12,13,14,15},{12,13,16,0},{12,14,17,0},
  {12,15,0,0},{13,16,18,0},{14,17,19,0},{16,18,20,0},{17,19,21,0},{18,20,22,0},
  {19,21,23,0},{20,22,0,0},{21,23,0,0}};

__device__ __forceinline__ float waveReduce(float v) {
  #pragma unroll
  for (int off = 32; off > 0; off >>= 1) v += __shfl_down(v, off, 64);
  return v;
}
__device__ __forceinline__ unsigned short f2bf(float x) {
  union { float f; unsigned u; } v; v.f = x;
  unsigned r = v.u + 0x7FFFu + ((v.u >> 16) & 1u);
  return (unsigned short)(r >> 16);
}
__device__ __forceinline__ float bf2f(unsigned short h) {
  union { unsigned u; float f; } v; v.u = ((unsigned)h) << 16; return v.f;
}

// ---- kPre: blocks 0..49 pose math (4 p/block) -> G' + qm bf16 hi/lo planes;
//      blocks 50..76: W_change^T, RA, E_Wi/E_W/E_A partials, pad zeroing ----
__global__ __launch_bounds__(256) void kPre(const float* __restrict__ J,
                                            const float* __restrict__ theta,
                                            const float* __restrict__ beta2,
                                            const float* __restrict__ Wp,
                                            const float* __restrict__ Wi,
                                            const float* __restrict__ A,
                                            float* __restrict__ ws) {
  unsigned short* qbh = (unsigned short*)ws + QBH_OFF_U;
  unsigned short* qbl = (unsigned short*)ws + QBL_OFF_U;
  int b = blockIdx.x;
  if (b < 50) {
    __shared__ float Gl[4][24][12];
    __shared__ float Gg[4][24][12];
    __shared__ float q[4][24][4];
    int w = threadIdx.x >> 6, t = threadIdx.x & 63;
    int p = b*4 + w;
    if (t < 24) {
      float x = theta[p*72 + 3*t + 0];
      float y = theta[p*72 + 3*t + 1];
      float z = theta[p*72 + 3*t + 2];
      float n2 = x*x + y*y + z*z;
      float ang = fmaxf(sqrtf(n2), 1e-8f);
      float ia = 1.f/ang;
      float ax = x*ia, ay = y*ia, az = z*ia;
      float c = cosf(ang), s = sinf(ang), C = 1.f - c;
      float jx = J[p*72+3*t], jy = J[p*72+3*t+1], jz = J[p*72+3*t+2];
      float tx = jx, ty = jy, tz = jz;
      if (t > 0) {
        int par = c_PARENT[t];
        tx -= J[p*72+3*par]; ty -= J[p*72+3*par+1]; tz -= J[p*72+3*par+2];
      }
      Gl[w][t][0]=c+C*ax*ax;   Gl[w][t][1]=C*ax*ay-s*az; Gl[w][t][2]=C*ax*az+s*ay; Gl[w][t][3]=tx;
      Gl[w][t][4]=C*ax*ay+s*az;Gl[w][t][5]=c+C*ay*ay;    Gl[w][t][6]=C*ay*az-s*ax; Gl[w][t][7]=ty;
      Gl[w][t][8]=C*ax*az-s*ay;Gl[w][t][9]=C*ay*az+s*ax; Gl[w][t][10]=c+C*az*az;   Gl[w][t][11]=tz;
      float ang2 = sqrtf(fmaxf(n2, 1e-16f));
      float inv2 = 1.f/ang2;
      float s2 = sinf(0.5f*ang2);
      q[w][t][0] = x*inv2*s2; q[w][t][1] = y*inv2*s2; q[w][t][2] = z*inv2*s2;
      q[w][t][3] = cosf(0.5f*ang2) - 1.f;
    }
    __syncthreads();
    for (int lev = 0; lev <= 8; lev++) {
      if (t < 24 && c_DEPTH[t] == lev) {
        if (lev == 0) {
          for (int i2 = 0; i2 < 12; i2++) Gg[w][0][i2] = Gl[w][0][i2];
        } else {
          int par = c_PARENT[t];
          for (int r = 0; r < 3; r++) {
            float g0 = Gg[w][par][r*4+0], g1 = Gg[w][par][r*4+1];
            float g2 = Gg[w][par][r*4+2], g3 = Gg[w][par][r*4+3];
            for (int c2 = 0; c2 < 4; c2++) {
              float v = g0*Gl[w][t][0+c2] + g1*Gl[w][t][4+c2] + g2*Gl[w][t][8+c2];
              if (c2 == 3) v += g3;
              Gg[w][t][r*4+c2] = v;
            }
          }
        }
      }
      __syncthreads();
    }
    if (t < 24) {
      float jx = J[p*72+3*t], jy = J[p*72+3*t+1], jz = J[p*72+3*t+2];
      float* gp = ws + G_OFF + p*288 + t*12;
      #pragma unroll
      for (int r = 0; r < 3; r++) {
        float off = Gg[w][t][r*4+0]*jx + Gg[w][t][r*4+1]*jy + Gg[w][t][r*4+2]*jz;
        Gg[w][t][r*4+3] -= off;
      }
      #pragma unroll
      for (int i2 = 0; i2 < 12; i2++) gp[i2] = Gg[w][t][i2];
    }
    __syncthreads();
    float b2 = beta2[0];
    for (int e = t; e < KDIM; e += 64) {
      int j = e / 17, l = e - 17*j;
      int k = j + 1;
      float val = 0.f;
      if (l < 4*c_LEN[j] + 1) {
        if (l < 16) {
          int sidx = l >> 2, cc = l & 3;
          if (sidx < c_LEN[k]) val = q[w][c_NBR[k][sidx]][cc];
        }
        if (l == 4*c_LEN[k]) val += b2;
      }
      unsigned short hi = f2bf(val);
      unsigned short lo = f2bf(val - bf2f(hi));
      qbh[p*KPAD + e] = hi;
      qbl[p*KPAD + e] = lo;
    }
    for (int e = KDIM + t; e < KPAD; e += 64) {   // k pad
      qbh[p*KPAD + e] = 0; qbl[p*KPAD + e] = 0;
    }
  } else {
    int d = b - 50;                        // 0..26
    int t = threadIdx.x;
    int n = d*256 + t;
    float ewi = 0.f, ew = 0.f, ea = 0.f;
    if (n < NV) {
      float wv[24]; float sum = 0.f;
      const float4* wp4 = (const float4*)(Wp + n*24);
      #pragma unroll
      for (int i = 0; i < 6; i++) {
        float4 v4 = wp4[i];
        wv[4*i+0] = fmaxf(v4.x, 0.f); wv[4*i+1] = fmaxf(v4.y, 0.f);
        wv[4*i+2] = fmaxf(v4.z, 0.f); wv[4*i+3] = fmaxf(v4.w, 0.f);
        sum += wv[4*i+0]+wv[4*i+1]+wv[4*i+2]+wv[4*i+3];
      }
      float inv = 1.f/(sum + 1e-8f);
      #pragma unroll
      for (int k = 0; k < 24; k++) {
        float wc = wv[k]*inv;
        ws[WT_OFF + k*NV + n] = wc;
        ew += fabsf(wc);
        float dd = wc - Wi[n*24+k];
        ewi += dd*dd;
      }
    }
    for (int i = d*256 + t; i < 23*NV; i += 27*256) ea += fabsf(A[i]);
    // RA[j][m] = relu(A[j][m/3]), pad cols 0
    for (int i = d*256 + t; i < 23*TP_STRIDE; i += 27*256) {
      int j = i / TP_STRIDE, m = i - j*TP_STRIDE;
      float v = 0.f;
      if (m < M_TOT) v = fmaxf(A[j*NV + m/3], 0.f);
      ws[RA_OFF + i] = v;
    }
    // zero qm bf16 pad rows p = 200..255
    for (int i = d*256 + t; i < 56*KPAD; i += 27*256) {
      qbh[200*KPAD + i] = 0; qbl[200*KPAD + i] = 0;
    }
    __shared__ float red[3][4];
    int lane = t & 63, wv2 = t >> 6;
    ewi = waveReduce(ewi); ew = waveReduce(ew); ea = waveReduce(ea);
    if (lane == 0) { red[0][wv2] = ewi; red[1][wv2] = ew; red[2][wv2] = ea; }
    __syncthreads();
    if (t == 0) {
      ws[WIP_OFF + d] = red[0][0]+red[0][1]+red[0][2]+red[0][3];
      ws[EWP_OFF + d] = red[1][0]+red[1][1]+red[1][2]+red[1][3];
      ws[EAP_OFF + d] = red[2][0]+red[2][1]+red[2][2]+red[2][3];
    }
  }
}

// ---- kB: TP(256 x 20672) = qm(256x391) @ (K ⊙ RA)(391x20672)
//      split-bf16 MFMA (hi/lo, 3 terms). Tile 128p x 64m, grid (323, 2). ----
__global__ __launch_bounds__(256) void kB(const float* __restrict__ K,
                                          float* __restrict__ ws) {
  __shared__ unsigned short Bh[64*32];
  __shared__ unsigned short Bl[64*32];
  __shared__ float ek[23];
  const unsigned short* qbh = (const unsigned short*)ws + QBH_OFF_U;
  const unsigned short* qbl = (const unsigned short*)ws + QBL_OFF_U;
  float* __restrict__ TP = ws + TP_OFF;

  const int tid = threadIdx.x;
  const int bx = blockIdx.x;                 // m-tile
  const int py = blockIdx.y;                 // p-tile (0/1)
  const int m0 = bx * 64;
  const int w = tid >> 6, lane = tid & 63;
  const int r = lane & 15, qd = lane >> 4;   // MFMA row/col and quad
  const int pbase = py*128 + w*32;
  const int c4 = tid & 15, pr = tid >> 4;    // staging mapping

  if (tid < 23) ek[tid] = 0.f;
  __syncthreads();

  f32x4 acc[2][4];
  #pragma unroll
  for (int h = 0; h < 2; h++)
    #pragma unroll
    for (int f = 0; f < 4; f++) acc[h][f] = (f32x4){0.f,0.f,0.f,0.f};

  const int aoff0 = (pbase + r) * KPAD + qd * 8;
  const int aoff1 = aoff0 + 16 * KPAD;

  for (int ks = 0; ks < 13; ks++) {
    if (ks) __syncthreads();
    {
      int mm = m0 + 4*c4;
      int kg0 = ks*32 + 2*pr, kg1 = kg0 + 1;
      float ka[4] = {0,0,0,0}, kb[4] = {0,0,0,0};
      float wa[4] = {0,0,0,0}, wb[4] = {0,0,0,0};
      float sq0 = 0.f, sq1 = 0.f;
      if (kg0 < KDIM) {
        int j = kg0 / 17;
        const float* kr = K + (size_t)kg0*M_TOT + mm;
        if (mm + 3 < M_TOT) {
          float2 x = *(const float2*)kr; float2 y = *(const float2*)(kr+2);
          ka[0]=x.x; ka[1]=x.y; ka[2]=y.x; ka[3]=y.y;
        } else {
          #pragma unroll
          for (int i = 0; i < 4; i++) if (mm+i < M_TOT) ka[i] = kr[i];
        }
        const float* rr = ws + RA_OFF + (size_t)j*TP_STRIDE + mm;
        float4 ra = *(const float4*)rr;
        wa[0]=ka[0]*ra.x; wa[1]=ka[1]*ra.y; wa[2]=ka[2]*ra.z; wa[3]=ka[3]*ra.w;
        sq0 = ka[0]*ka[0]+ka[1]*ka[1]+ka[2]*ka[2]+ka[3]*ka[3];
      }
      if (kg1 < KDIM) {
        int j = kg1 / 17;
        const float* kr = K + (size_t)kg1*M_TOT + mm;
        if (mm + 3 < M_TOT) {
          float2 x = *(const float2*)kr; float2 y = *(const float2*)(kr+2);
          kb[0]=x.x; kb[1]=x.y; kb[2]=y.x; kb[3]=y.y;
        } else {
          #pragma unroll
          for (int i = 0; i < 4; i++) if (mm+i < M_TOT) kb[i] = kr[i];
        }
        const float* rr = ws + RA_OFF + (size_t)j*TP_STRIDE + mm;
        float4 ra = *(const float4*)rr;
        wb[0]=kb[0]*ra.x; wb[1]=kb[1]*ra.y; wb[2]=kb[2]*ra.z; wb[3]=kb[3]*ra.w;
        sq1 = kb[0]*kb[0]+kb[1]*kb[1]+kb[2]*kb[2]+kb[3]*kb[3];
      }
      #pragma unroll
      for (int i = 0; i < 4; i++) {
        unsigned short h0 = f2bf(wa[i]); unsigned short l0 = f2bf(wa[i] - bf2f(h0));
        unsigned short h1 = f2bf(wb[i]); unsigned short l1 = f2bf(wb[i] - bf2f(h1));
        int mi = 4*c4 + i;
        int physdw = (pr + 4*(c4 & 3)) & 15;        // bank swizzle
        *(unsigned*)&Bh[mi*32 + physdw*2] = (unsigned)h0 | ((unsigned)h1 << 16);
        *(unsigned*)&Bl[mi*32 + physdw*2] = (unsigned)l0 | ((unsigned)l1 << 16);
      }
      if (py == 0) {
        #pragma unroll
        for (int off = 1; off <= 8; off <<= 1) {
          sq0 += __shfl_xor(sq0, off, 64);
          sq1 += __shfl_xor(sq1, off, 64);
        }
        if ((lane & 15) == 0) {
          if (kg0 < KDIM) atomicAdd(&ek[kg0/17], sq0);
          if (kg1 < KDIM) atomicAdd(&ek[kg1/17], sq1);
        }
      }
    }
    __syncthreads();
    {
      int kso = ks * 32;
      short8 ah0 = *(const short8*)(qbh + aoff0 + kso);
      short8 ah1 = *(const short8*)(qbh + aoff1 + kso);
      short8 al0 = *(const short8*)(qbl + aoff0 + kso);
      short8 al1 = *(const short8*)(qbl + aoff1 + kso);
      short8 bh[4], bl[4];
      const int rotdw = 4*((r >> 2) & 3);
      #pragma unroll
      for (int f = 0; f < 4; f++) {
        int m = f*16 + r;
        int physdw = (4*qd + rotdw) & 15;
        bh[f] = *(const short8*)(&Bh[m*32 + physdw*2]);
        bl[f] = *(const short8*)(&Bl[m*32 + physdw*2]);
      }
      #pragma unroll
      for (int f = 0; f < 4; f++) {
        acc[0][f] = __builtin_amdgcn_mfma_f32_16x16x32_bf16(ah0, bh[f], acc[0][f], 0, 0, 0);
        acc[1][f] = __builtin_amdgcn_mfma_f32_16x16x32_bf16(ah1, bh[f], acc[1][f], 0, 0, 0);
      }
      #pragma unroll
      for (int f = 0; f < 4; f++) {
        acc[0][f] = __builtin_amdgcn_mfma_f32_16x16x32_bf16(ah0, bl[f], acc[0][f], 0, 0, 0);
        acc[1][f] = __builtin_amdgcn_mfma_f32_16x16x32_bf16(ah1, bl[f], acc[1][f], 0, 0, 0);
      }
      #pragma unroll
      for (int f = 0; f < 4; f++) {
        acc[0][f] = __builtin_amdgcn_mfma_f32_16x16x32_bf16(al0, bh[f], acc[0][f], 0, 0, 0);
        acc[1][f] = __builtin_amdgcn_mfma_f32_16x16x32_bf16(al1, bh[f], acc[1][f], 0, 0, 0);
      }
    }
  }
  #pragma unroll
  for (int h = 0; h < 2; h++)
    #pragma unroll
    for (int f = 0; f < 4; f++)
      #pragma unroll
      for (int g = 0; g < 4; g++) {
        int p = pbase + h*16 + qd*4 + g;
        TP[(size_t)p*TP_STRIDE + m0 + f*16 + r] = acc[h][f][g];
      }
  __syncthreads();
  if (py == 0 && tid < 23)
    ws[EKP_OFF + tid*NMTILE + bx] = ek[tid];
}

// ---- kC: skinning + verts + E_D. 2 verts/thread, 1 p/block, grid (14,200).
//      VGPR-lean (M=24) for high occupancy; G' via LDS broadcast. ----
__global__ __launch_bounds__(256) void kC(const float* __restrict__ V,
                                          const float* __restrict__ T,
                                          float* __restrict__ ws,
                                          float* __restrict__ out) {
  int p = blockIdx.y;
  int n0 = (blockIdx.x*256 + threadIdx.x) * 2;
  __shared__ float Gs[288];
  __shared__ float tmp[4];
  if (threadIdx.x < 72)
    ((float4*)Gs)[threadIdx.x] = ((const float4*)(ws + G_OFF + p*288))[threadIdx.x];
  __syncthreads();
  float ed = 0.f;
  if (n0 < NV) {   // NV even -> n0+1 also valid
    float M0[12], M1[12];
    #pragma unroll
    for (int i = 0; i < 12; i++) { M0[i] = 0.f; M1[i] = 0.f; }
    const float* Wt = ws + WT_OFF;
    #pragma unroll
    for (int k = 0; k < 24; k++) {
      float2 wv = *(const float2*)(Wt + k*NV + n0);   // coalesced 8B/lane
      float4 g0 = *(const float4*)(Gs + k*12 + 0);    // wave-uniform broadcast
      float4 g1 = *(const float4*)(Gs + k*12 + 4);
      float4 g2 = *(const float4*)(Gs + k*12 + 8);
      M0[0] = fmaf(wv.x, g0.x, M0[0]); M0[1]  = fmaf(wv.x, g0.y, M0[1]);
      M0[2] = fmaf(wv.x, g0.z, M0[2]); M0[3]  = fmaf(wv.x, g0.w, M0[3]);
      M0[4] = fmaf(wv.x, g1.x, M0[4]); M0[5]  = fmaf(wv.x, g1.y, M0[5]);
      M0[6] = fmaf(wv.x, g1.z, M0[6]); M0[7]  = fmaf(wv.x, g1.w, M0[7]);
      M0[8] = fmaf(wv.x, g2.x, M0[8]); M0[9]  = fmaf(wv.x, g2.y, M0[9]);
      M0[10]= fmaf(wv.x, g2.z, M0[10]);M0[11] = fmaf(wv.x, g2.w, M0[11]);
      M1[0] = fmaf(wv.y, g0.x, M1[0]); M1[1]  = fmaf(wv.y, g0.y, M1[1]);
      M1[2] = fmaf(wv.y, g0.z, M1[2]); M1[3]  = fmaf(wv.y, g0.w, M1[3]);
      M1[4] = fmaf(wv.y, g1.x, M1[4]); M1[5]  = fmaf(wv.y, g1.y, M1[5]);
      M1[6] = fmaf(wv.y, g1.z, M1[6]); M1[7]  = fmaf(wv.y, g1.w, M1[7]);
      M1[8] = fmaf(wv.y, g2.x, M1[8]); M1[9]  = fmaf(wv.y, g2.y, M1[9]);
      M1[10]= fmaf(wv.y, g2.z, M1[10]);M1[11] = fmaf(wv.y, g2.w, M1[11]);
    }
    size_t tb = (size_t)p*M_TOT + 3*n0;       // T, V, out base (8B aligned)
    size_t pb = (size_t)p*TP_STRIDE + 3*n0;   // TP base (8B aligned)
    float2 q0 = *(const float2*)(ws + TP_OFF + pb);
    float2 q1 = *(const float2*)(ws + TP_OFF + pb + 2);
    float2 q2 = *(const float2*)(ws + TP_OFF + pb + 4);
    float2 s0 = *(const float2*)(T + tb);
    float2 s1 = *(const float2*)(T + tb + 2);
    float2 s2 = *(const float2*)(T + tb + 4);
    float ta0 = q0.x + s0.x, ta1 = q0.y + s0.y, ta2 = q1.x + s1.x;
    float tb0 = q1.y + s1.y, tb1 = q2.x + s2.x, tb2 = q2.y + s2.y;
    float v00 = M0[0]*ta0 + M0[1]*ta1 + M0[2]*ta2  + M0[3];
    float v01 = M0[4]*ta0 + M0[5]*ta1 + M0[6]*ta2  + M0[7];
    float v02 = M0[8]*ta0 + M0[9]*ta1 + M0[10]*ta2 + M0[11];
    float v10 = M1[0]*tb0 + M1[1]*tb1 + M1[2]*tb2  + M1[3];
    float v11 = M1[4]*tb0 + M1[5]*tb1 + M1[6]*tb2  + M1[7];
    float v12 = M1[8]*tb0 + M1[9]*tb1 + M1[10]*tb2 + M1[11];
    out[1+tb+0] = v00; out[1+tb+1] = v01; out[1+tb+2] = v02;
    out[1+tb+3] = v10; out[1+tb+4] = v11; out[1+tb+5] = v12;
    float2 x0 = *(const float2*)(V + tb);
    float2 x1 = *(const float2*)(V + tb + 2);
    float2 x2 = *(const float2*)(V + tb + 4);
    float d0 = x0.x-v00, d1 = x0.y-v01, d2 = x1.x-v02;
    float d3 = x1.y-v10, d4 = x2.x-v11, d5 = x2.y-v12;
    ed = d0*d0 + d1*d1 + d2*d2 + d3*d3 + d4*d4 + d5*d5;
  }
  ed = waveReduce(ed);
  int lane = threadIdx.x & 63, w = threadIdx.x >> 6;
  if (lane == 0) tmp[w] = ed;
  __syncthreads();
  if (threadIdx.x == 0)
    ws[EDP_OFF + blockIdx.y*14 + blockIdx.x] = tmp[0]+tmp[1]+tmp[2]+tmp[3];
}

// ---- kF1: parallel partial reductions (25 blocks) ----
__global__ __launch_bounds__(256) void kF1(float* __restrict__ ws) {
  __shared__ float sb[4];
  int b = blockIdx.x, t = threadIdx.x, lane = t & 63, w = t >> 6;
  if (b < 23) {                       // E_K slice sums
    float s = 0.f;
    for (int i = t; i < NMTILE; i += 256) s += ws[EKP_OFF + b*NMTILE + i];
    s = waveReduce(s);
    if (lane == 0) sb[w] = s;
    __syncthreads();
    if (t == 0) ws[RED_OFF + b] = sb[0]+sb[1]+sb[2]+sb[3];
  } else if (b == 23) {               // E_D
    float s = 0.f;
    for (int i = t; i < 2800; i += 256) s += ws[EDP_OFF + i];
    s = waveReduce(s);
    if (lane == 0) sb[w] = s;
    __syncthreads();
    if (t == 0) ws[RED_OFF + 23] = sb[0]+sb[1]+sb[2]+sb[3];
  } else {                            // E_Wi / E_W / E_A (27 partials each)
    if (w == 0) {
      float s = (lane < 27) ? ws[WIP_OFF + lane] : 0.f;
      s = waveReduce(s);
      if (lane == 0) ws[RED_OFF + 24] = s;
    } else if (w == 1) {
      float s = (lane < 27) ? ws[EWP_OFF + lane] : 0.f;
      s = waveReduce(s);
      if (lane == 0) ws[RED_OFF + 25] = s;
    } else if (w == 2) {
      float s = (lane < 27) ? ws[EAP_OFF + lane] : 0.f;
      s = waveReduce(s);
      if (lane == 0) ws[RED_OFF + 26] = s;
    }
  }
}

// ---- kF2: final combine ----
__global__ void kF2(const int* __restrict__ epoch, const float* __restrict__ ws,
                    float* __restrict__ out) {
  int t = threadIdx.x;
  float s = (t < 23) ? sqrtf(ws[RED_OFF + t]) : 0.f;
  s = waveReduce(s);
  if (t == 0) {
    float e    = (float)epoch[0];
    float g_wi = 0.1f   * expf(-0.1f  * e);
    float g_w  = 0.002f * expf(-0.008f* e);
    float g_a  = 0.001f * expf(-0.008f* e);
    float g_k  = 0.1f   * expf(-0.008f* e);
    out[0] = ws[RED_OFF+23] + g_wi*ws[RED_OFF+24] + g_w*ws[RED_OFF+25]
           + g_a*ws[RED_OFF+26] + g_k*s;
  }
}

extern "C" void kernel_launch(void* const* d_in, const int* in_sizes, int n_in,
                              void* d_out, int out_size, void* d_ws, size_t ws_size,
                              hipStream_t stream) {
  const float* V     = (const float*)d_in[0];
  const float* T     = (const float*)d_in[1];
  const float* J     = (const float*)d_in[2];
  const float* theta = (const float*)d_in[3];
  const float* Wp    = (const float*)d_in[4];
  const float* Wi    = (const float*)d_in[5];
  const float* A     = (const float*)d_in[6];
  const float* K     = (const float*)d_in[7];
  const float* b2    = (const float*)d_in[8];
  const int*   epoch = (const int*)d_in[9];
  float* out = (float*)d_out;
  float* ws  = (float*)d_ws;
  // needs ~24.5 MB workspace

  hipLaunchKernelGGL(kPre, dim3(77),         dim3(256), 0, stream,
                     J, theta, b2, Wp, Wi, A, ws);
  hipLaunchKernelGGL(kB,   dim3(NMTILE, 2),  dim3(256), 0, stream, K, ws);
  hipLaunchKernelGGL(kC,   dim3(14, PREG),   dim3(256), 0, stream, V, T, ws, out);
  hipLaunchKernelGGL(kF1,  dim3(25),         dim3(256), 0, stream, ws);
  hipLaunchKernelGGL(kF2,  dim3(1),          dim3(64),  0, stream, epoch, ws, out);
}